// Round 5
// baseline (150.863 us; speedup 1.0000x reference)
//
#include <hip/hip_runtime.h>
#include <math.h>

#define Hh 128
#define Ww 128
#define HW (Hh*Ww)
#define Bn 4
#define Cn 64
#define On 64
#define KP 200                // LDS A-row stride (shorts): 192 data + 8 pad
                              // (==0 mod 8 for 16B ds_read_b128; row stride
                              //  100 dw == 4 mod 32 banks -> 2-way max = free)
#define OMP 66                // padded px stride for sOM (f16), 64 px
#define NBLK 1024             // dcn grid (half-row blocks)
#define NPART 2048            // part columns: blk*2 + px-half

typedef __attribute__((ext_vector_type(8))) short bf16x8;
typedef __attribute__((ext_vector_type(4))) float f32x4;
typedef __attribute__((ext_vector_type(4))) unsigned short u16x4;
typedef __attribute__((ext_vector_type(2))) unsigned u32x2;
typedef __attribute__((ext_vector_type(4))) unsigned u32x4;

// fp32 -> bf16 round-to-nearest-even
static __device__ __forceinline__ unsigned short f2bf(float f) {
    unsigned u = __builtin_bit_cast(unsigned, f);
    u += 0x7FFFu + ((u >> 16) & 1u);
    return (unsigned short)(u >> 16);
}
static __device__ __forceinline__ short f2h(float f) {
    _Float16 h = (_Float16)f;
    return __builtin_bit_cast(short, h);
}
static __device__ __forceinline__ float h2f(short s) {
    return (float)__builtin_bit_cast(_Float16, s);
}
static __device__ __forceinline__ float bflo(unsigned d) {
    return __builtin_bit_cast(float, d << 16);
}
static __device__ __forceinline__ float bfhi(unsigned d) {
    return __builtin_bit_cast(float, d & 0xFFFF0000u);
}

// workspace layout (bytes): xtb(8M) | conv(16M) | part(1M) | ss | owT | dwT
#define XTB_BYTES   ((size_t)Bn*HW*64*2)
#define CONV_BYTES  ((size_t)Bn*On*HW*4)
#define PART_BYTES  ((size_t)128*NPART*4)

// ---------------------------------------------------------------------------
// Prep: blocks 0..511 = NCHW->NHWC bf16 transpose (one (b,h) row each);
//       blocks 512..727 = weight pack bf16 tap-major [o][tap][c].
// ---------------------------------------------------------------------------
__global__ __launch_bounds__(256) void prep_k(
    const float* __restrict__ x,  const float* __restrict__ ow,
    const float* __restrict__ dw, unsigned* __restrict__ xtb,
    short* __restrict__ owT,      short* __restrict__ dwT)
{
    int blk = blockIdx.x;
    int t = threadIdx.x;
    if (blk < 512) {
        int b = blk >> 7, h = blk & 127;
        __shared__ float sT[64 * 133];
        const float* xp = x + (size_t)b * Cn * HW + (size_t)h * Ww;
#pragma unroll
        for (int it = 0; it < 32; ++it) {
            int idx = t + 256 * it;        // c(6b) | w(7b)
            int c = idx >> 7, w = idx & 127;
            sT[c * 133 + w] = xp[(size_t)c * HW + w];
        }
        __syncthreads();
        unsigned* op = xtb + (size_t)blk * Ww * 32;   // 32 dwords (64 bf16)/px
#pragma unroll
        for (int it = 0; it < 16; ++it) {
            int idx = t + 256 * it;        // w(7b) | cp(5b)
            int w = idx >> 5, cp = idx & 31;
            unsigned lo = f2bf(sT[(2 * cp) * 133 + w]);
            unsigned hi = f2bf(sT[(2 * cp + 1) * 133 + w]);
            op[(size_t)w * 32 + cp] = lo | (hi << 16);
        }
    } else {
        int u = (blk - 512) * 4 + (t >> 6);   // 0..863
        int c = t & 63;
        if (u < 288) {
            int o = u / 9, kk = u % 9;
            float v = (o < 27) ? ow[(size_t)o * 576 + c * 9 + kk] : 0.0f;
            owT[(size_t)u * 64 + c] = (short)f2bf(v);
        } else {
            int u2 = u - 288;
            int o = u2 / 9, kk = u2 % 9;
            dwT[(size_t)u2 * 64 + c] = (short)f2bf(dw[(size_t)o * 576 + c * 9 + kk]);
        }
    }
}

// ---------------------------------------------------------------------------
// Fused: offset-conv GEMM -> per-thread bilinear prep -> sampling fill ->
// DCN GEMM -> conv store + BN stats partials (transposed part).
// Block = HALF-row (64 px), grid 1024, XCD-swizzled. x is bf16 NHWC.
// Structure = R2/R4 (13 barriers, wave owns o-tile in GEMMs). R3's
// barrier-free wave-private flip REGRESSED 54->81 us (per-ks global B-frag
// loads exposed L1/L2 latency on MFMA path). DO NOT re-flip.
// R5 (this round): 8 WAVES / 512 THREADS per block, same tile & structure.
// 4 blocks/CU x 8 waves = 32 waves/CU (HW max) vs 16 before -- doubles TLP
// for gather-latency hiding. Accumulator footprint halves (acc[2], oacc[1])
// to keep VGPR <= 64 (8 waves/SIMD requirement). Accumulation order per
// (px,o) unchanged -> bit-identical conv output.
// CRITICAL #1: no __launch_bounds__ min-waves arg (R3 spill disaster).
// CRITICAL #2: wave id readfirstlane'd (R4 divergent-uniform trap).
// MFMA 16x16x32 bf16 (validated R8-R12):
//   A lane=[m=l15][k=quad*8+j]; B lane=[k=quad*8+j][n=l15];
//   D lane=[row=quad*4+r][col=l15].
// LDS: sA 25600 (sOMh 3588 aliased in) + prepQ 4608 + prepC 1152 = 31360 B.
// ---------------------------------------------------------------------------
__global__ __launch_bounds__(512) void dcn_fused_k(
    const unsigned* __restrict__ xtb, const short* __restrict__ owT,
    const float* __restrict__ ob,     const short* __restrict__ dwT,
    float* __restrict__ conv,         float* __restrict__ part)
{
    int raw  = blockIdx.x;
    int blk  = ((raw & 7) << 7) | (raw >> 3);   // b(2b) | h(7b) | half(1b)
    int half = blk & 1;
    int h    = (blk >> 1) & 127;
    int b    = blk >> 8;
    int px0  = half * 64;
    int t    = threadIdx.x;
    int lane = t & 63;
    int quad = lane >> 4;
    int l15  = lane & 15;
    int qw   = lane >> 4;          // quarter-wave unit id (phase 3 fill)
    int cl2  = lane & 15;          // dword-PAIR (4-channel) index, phase 3
    int og   = lane >> 3;          // eighth-wave unit id (phase 1 fill)
    int li   = lane & 7;           // dwordx4 lane, phase 1
    int w_s  = __builtin_amdgcn_readfirstlane(t >> 6);   // 0..7 (SGPR)

    __shared__ __align__(16) short sA[64 * KP];               // 25600 B (bf16)
    __shared__ __align__(16) unsigned short prepQ[576 * 4];   //  4608 B {idx,w00,w01,w10}
    __shared__ __align__(16) unsigned short prepC[576];       //  1152 B {w11}
    short* sOMh = sA;   // 27*OMP+12 = 1794 shorts, aliased (sA dead in phase 2)

    const unsigned* xbd = xtb + (size_t)b * HW * 32;               // dword view
    unsigned* sAd = (unsigned*)sA;                                 // row = 100 dw

    // ================= Phase 1: offset conv GEMM (M=64, N=32) ============
    // wave = (o-tile nt_o: 16 o) x (px-quarter mq: 16 px)
    int nt_o = w_s & 1;
    int mq   = w_s >> 1;           // 0..3
    int o_ow = nt_o * 16 + l15;
    f32x4 oacc = {0,0,0,0};

    for (int ck = 0; ck < 3; ++ck) {
        int yy = h + ck - 1;
        bool rowok = ((unsigned)yy < (unsigned)Hh);
        // ---- im2col fill: 192 units (kkl(2b)|px(6b)); 8 waves x 8 units x
        //      (8 lanes x dwordx4) -> 3 iters
#pragma unroll
        for (int it = 0; it < 3; ++it) {
            int unit = (it * 8 + w_s) * 8 + og;   // 0..191
            int kkl = unit >> 6, px = unit & 63;
            int xx = px0 + px + kkl - 1;
            bool valid = rowok && ((unsigned)xx < (unsigned)Ww);
            u32x4 v = {0u, 0u, 0u, 0u};
            if (valid)
                v = *(const u32x4*)&xbd[(((size_t)yy << 7) + xx) * 32 + li * 4];
            *(u32x4*)&sAd[px * 100 + kkl * 32 + li * 4] = v;
        }
        __syncthreads();
#pragma unroll
        for (int ks = 0; ks < 6; ++ks) {
            int kk = ck * 3 + (ks >> 1);
            bf16x8 bfr = *(const bf16x8*)&owT[((size_t)o_ow * 9 + kk) * 64
                                             + (ks & 1) * 32 + quad * 8];
            bf16x8 a = *(const bf16x8*)&sA[(mq * 16 + l15) * KP
                                           + ks * 32 + quad * 8];
            oacc = __builtin_amdgcn_mfma_f32_16x16x32_bf16(a, bfr, oacc, 0, 0, 0);
        }
        __syncthreads();
    }
    // ---- D -> sOMh (+bias), f16; px = mq*16 + quad*4 + r
    // (sA is dead here: last chunk's MFMAs completed before the final sync)
    if (o_ow < 27) {
        float bias = ob[o_ow];
        int pxb = mq * 16 + quad * 4;
#pragma unroll
        for (int r = 0; r < 4; ++r)
            sOMh[o_ow * OMP + pxb + r] = f2h(oacc[r] + bias);
    }
    __syncthreads();

    // ================= Phase 2: per-thread bilinear prep -> LDS ==========
    // 576 units = tap(9) x px(64); thread owns u = t, t+512(<576).
    // Validity factorizes per-axis onto physical rows/cols (yb,yb+1)/(xb,xb+1);
    // corner weight = wr*wc, sigmoid mask folded into wr. Base idx yb*128+xb;
    // corners {+0,+1,+128,+129} always in-bounds.
#pragma unroll
    for (int i = 0; i < 2; ++i) {
        int u = t + 512 * i;
        if (u < 576) {
            int kk = u >> 6, px = u & 63;
            float ox = h2f((short)sOMh[kk * OMP + px]);
            float oy = h2f((short)sOMh[(9 + kk) * OMP + px]);
            float mr = h2f((short)sOMh[(18 + kk) * OMP + px]);
            float m  = 1.0f / (1.0f + __expf(-mr));
            float py  = (float)(h - 1 + (kk / 3)) + oy;
            float pxf = (float)(px0 + px - 1 + (kk % 3)) + ox;
            float y0f = floorf(py), x0f = floorf(pxf);
            int y0 = (int)y0f, x0 = (int)x0f;
            float wy = py - y0f, wx = pxf - x0f;
            int yb = min(max(y0, 0), Hh - 2);
            int xb = min(max(x0, 0), Ww - 2);
            float wr0 = (yb == y0) ? (1.0f - wy) : ((yb     == y0 + 1) ? wy : 0.0f);
            float wr1 = (yb == y0) ? wy          : ((yb + 1 == y0    ) ? (1.0f - wy) : 0.0f);
            float wc0 = (xb == x0) ? (1.0f - wx) : ((xb     == x0 + 1) ? wx : 0.0f);
            float wc1 = (xb == x0) ? wx          : ((xb + 1 == x0    ) ? (1.0f - wx) : 0.0f);
            wr0 *= m; wr1 *= m;
            prepQ[u * 4 + 0] = (unsigned short)(yb * Ww + xb);
            prepQ[u * 4 + 1] = (unsigned short)f2h(wr0 * wc0);
            prepQ[u * 4 + 2] = (unsigned short)f2h(wr0 * wc1);
            prepQ[u * 4 + 3] = (unsigned short)f2h(wr1 * wc0);
            prepC[u]         = (unsigned short)f2h(wr1 * wc1);
        }
    }
    __syncthreads();

    // ================= Phase 3: sampling fill + DCN GEMM (M=64, N=64) ====
    // wave = (o-tile w_s&3: 16 o) x (px-half mh3: 32 px).
    // Fill: 8 waves x 4 units (16 lanes each) = 32 units/iter -> 6 iters;
    // lane owns 4 CHANNELS (dword pair). Per unit: b64+b16 broadcast
    // ds_read, ONE gather addr chain, 4x dwordx2 (128B/corner coalesced),
    // 16 FMA, 2x v_cvt_pk_bf16_f32, 1 ds_write_b64.
    int o_dw = (w_s & 3) * 16 + l15;
    int mh3  = w_s >> 2;           // px half 0/1
    f32x4 acc[2] = {{0,0,0,0},{0,0,0,0}};

    for (int ck = 0; ck < 3; ++ck) {
#pragma unroll
        for (int it = 0; it < 6; ++it) {
            int unit = (it * 8 + w_s) * 4 + qw;   // 0..191 within ck
            int kkl = unit >> 6, px = unit & 63;
            int uG = (ck * 3 + kkl) * 64 + px;    // global unit id
            u16x4 q = *(const u16x4*)&prepQ[uG * 4];     // broadcast ds_read_b64
            float w00 = h2f((short)q[1]);
            float w01 = h2f((short)q[2]);
            float w10 = h2f((short)q[3]);
            float w11 = h2f((short)prepC[uG]);           // broadcast ds_read_u16
            const unsigned* p0 = xbd + (size_t)q[0] * 32 + cl2 * 2;
            u32x2 d00 = *(const u32x2*)(p0);
            u32x2 d01 = *(const u32x2*)(p0 + 32);        // col+1 (+128 B)
            u32x2 d10 = *(const u32x2*)(p0 + 4096);      // row+1
            u32x2 d11 = *(const u32x2*)(p0 + 4128);      // row+1, col+1
            u32x2 pkv;
#pragma unroll
            for (int j = 0; j < 2; ++j) {
                float v0 = w00 * bflo(d00[j]) + w01 * bflo(d01[j])
                         + w10 * bflo(d10[j]) + w11 * bflo(d11[j]);
                float v1 = w00 * bfhi(d00[j]) + w01 * bfhi(d01[j])
                         + w10 * bfhi(d10[j]) + w11 * bfhi(d11[j]);
                unsigned pk;
                asm("v_cvt_pk_bf16_f32 %0, %1, %2" : "=v"(pk) : "v"(v0), "v"(v1));
                pkv[j] = pk;
            }
            *(u32x2*)&sAd[px * 100 + kkl * 32 + cl2 * 2] = pkv;
        }
        __syncthreads();
#pragma unroll
        for (int ks = 0; ks < 6; ++ks) {
            int kk = ck * 3 + (ks >> 1);
            bf16x8 bfr = *(const bf16x8*)&dwT[((size_t)o_dw * 9 + kk) * 64
                                              + (ks & 1) * 32 + quad * 8];
#pragma unroll
            for (int mt = 0; mt < 2; ++mt) {
                bf16x8 a = *(const bf16x8*)&sA[(mh3 * 32 + mt * 16 + l15) * KP
                                               + ks * 32 + quad * 8];
                acc[mt] = __builtin_amdgcn_mfma_f32_16x16x32_bf16(a, bfr, acc[mt], 0, 0, 0);
            }
        }
        __syncthreads();
    }

    // ================= Phase 4: store conv + stats partials =================
#pragma unroll
    for (int mt = 0; mt < 2; ++mt) {
        size_t idx = ((size_t)b * On + o_dw) * HW + (size_t)h * Ww
                   + px0 + mh3 * 32 + mt * 16 + quad * 4;
        *(f32x4*)(conv + idx) = acc[mt];
    }
    // per-o sums over this wave's 32 px; two waves per o-tile write
    // different part columns (blk*2 + mh3) -> no cross-wave reduce needed.
    float s1 = 0.0f, s2 = 0.0f;
#pragma unroll
    for (int mt = 0; mt < 2; ++mt) {
#pragma unroll
        for (int r = 0; r < 4; ++r) {
            float v = acc[mt][r];
            s1 += v;
            s2 += v * v;
        }
    }
    s1 += __shfl_down(s1, 32, 64);  s2 += __shfl_down(s2, 32, 64);
    s1 += __shfl_down(s1, 16, 64);  s2 += __shfl_down(s2, 16, 64);
    if (lane < 16) {
        part[(size_t)o_dw * NPART + blk * 2 + mh3]        = s1;
        part[(size_t)(64 + o_dw) * NPART + blk * 2 + mh3] = s2;
    }
}

// ---------------------------------------------------------------------------
// Fused BN stats + apply + ReLU.
// Grid 1024: o = idx&63, bq = idx>>6. Each block re-reduces its channel's
// part rows (16 KB, L2-hit) -> sc/sh, then applies BN+ReLU over a 4096-float
// slab of conv.
// ---------------------------------------------------------------------------
__global__ __launch_bounds__(256) void bnstats_k(
    const float* __restrict__ part, const float* __restrict__ gamma,
    const float* __restrict__ beta, const float* __restrict__ conv,
    float* __restrict__ out)
{
    int idx = blockIdx.x;
    int o  = idx & 63;
    int bq = idx >> 6;          // b = bq>>2, q = bq&3
    int t = threadIdx.x;
    float s1 = 0.0f, s2 = 0.0f;
#pragma unroll
    for (int i = 0; i < NPART / 256; ++i) {
        int j = t + 256 * i;
        s1 += part[(size_t)o * NPART + j];
        s2 += part[(size_t)(64 + o) * NPART + j];
    }
#pragma unroll
    for (int off = 32; off > 0; off >>= 1) {
        s1 += __shfl_down(s1, off, 64);
        s2 += __shfl_down(s2, off, 64);
    }
    __shared__ float r1[4], r2[4];
    __shared__ float sc_s, sh_s;
    if ((t & 63) == 0) { r1[t >> 6] = s1; r2[t >> 6] = s2; }
    __syncthreads();
    if (t == 0) {
        float S1 = r1[0] + r1[1] + r1[2] + r1[3];
        float S2 = r2[0] + r2[1] + r2[2] + r2[3];
        float n = (float)(Bn * HW);
        float mu = S1 / n;
        float var = S2 / n - mu * mu;
        float sc = gamma[o] * rsqrtf(var + 1e-5f);
        sc_s = sc;
        sh_s = beta[o] - mu * sc;
    }
    __syncthreads();
    float sc = sc_s, sh = sh_s;
    size_t base = (((size_t)(bq >> 2) * On + o) * HW + (size_t)(bq & 3) * 4096) / 4;
    const float4* cv = (const float4*)conv + base;
    float4* ov = (float4*)out + base;
#pragma unroll
    for (int i = 0; i < 4; ++i) {
        float4 v = cv[t + 256 * i];
        v.x = fmaxf(v.x * sc + sh, 0.0f);
        v.y = fmaxf(v.y * sc + sh, 0.0f);
        v.z = fmaxf(v.z * sc + sh, 0.0f);
        v.w = fmaxf(v.w * sc + sh, 0.0f);
        ov[t + 256 * i] = v;
    }
}

// ---------------------------------------------------------------------------
extern "C" void kernel_launch(void* const* d_in, const int* in_sizes, int n_in,
                              void* d_out, int out_size, void* d_ws, size_t ws_size,
                              hipStream_t stream)
{
    const float* x     = (const float*)d_in[0];
    const float* ow    = (const float*)d_in[1];
    const float* ob    = (const float*)d_in[2];
    const float* dw    = (const float*)d_in[3];
    // d_in[4] = dcn_b: cancels exactly under BN mean subtraction -> unused
    const float* gamma = (const float*)d_in[5];
    const float* beta  = (const float*)d_in[6];

    char* wsb = (char*)d_ws;
    unsigned* xtb = (unsigned*)wsb;
    float* conv = (float*)(wsb + XTB_BYTES);
    float* part = (float*)(wsb + XTB_BYTES + CONV_BYTES);
    short* owT  = (short*)(wsb + XTB_BYTES + CONV_BYTES + PART_BYTES + 512);
    short* dwT  = owT + 288 * 64;

    prep_k     <<<dim3(728),  dim3(256), 0, stream>>>(x, ow, dw, xtb, owT, dwT);
    dcn_fused_k<<<dim3(NBLK), dim3(512), 0, stream>>>(xtb, owT, ob, dwT, conv, part);
    bnstats_k  <<<dim3(1024), dim3(256), 0, stream>>>(part, gamma, beta, conv, (float*)d_out);
}

// Round 6
// 144.015 us; speedup vs baseline: 1.0476x; 1.0476x over previous
//
#include <hip/hip_runtime.h>
#include <math.h>

#define Hh 128
#define Ww 128
#define HW (Hh*Ww)
#define Bn 4
#define Cn 64
#define On 64
#define KP 200                // LDS A-row stride (shorts): 192 data + 8 pad
                              // (==0 mod 8 for 16B ds_read_b128; row stride
                              //  100 dw == 4 mod 32 banks -> 2-way max = free)
#define OMP 34                // padded px stride for sOM (f16), 32 px
#define NBLK 2048             // dcn grid (quarter-row blocks)
#define NPART 2048            // part columns: one per block

typedef __attribute__((ext_vector_type(8))) short bf16x8;
typedef __attribute__((ext_vector_type(4))) float f32x4;
typedef __attribute__((ext_vector_type(4))) unsigned short u16x4;
typedef __attribute__((ext_vector_type(2))) unsigned u32x2;
typedef __attribute__((ext_vector_type(4))) unsigned u32x4;

// fp32 -> bf16 round-to-nearest-even
static __device__ __forceinline__ unsigned short f2bf(float f) {
    unsigned u = __builtin_bit_cast(unsigned, f);
    u += 0x7FFFu + ((u >> 16) & 1u);
    return (unsigned short)(u >> 16);
}
static __device__ __forceinline__ short f2h(float f) {
    _Float16 h = (_Float16)f;
    return __builtin_bit_cast(short, h);
}
static __device__ __forceinline__ float h2f(short s) {
    return (float)__builtin_bit_cast(_Float16, s);
}
static __device__ __forceinline__ float bflo(unsigned d) {
    return __builtin_bit_cast(float, d << 16);
}
static __device__ __forceinline__ float bfhi(unsigned d) {
    return __builtin_bit_cast(float, d & 0xFFFF0000u);
}

// workspace layout (bytes): xtb(8M) | conv(16M) | part(1M) | ss | owT | dwT
#define XTB_BYTES   ((size_t)Bn*HW*64*2)
#define CONV_BYTES  ((size_t)Bn*On*HW*4)
#define PART_BYTES  ((size_t)128*NPART*4)

// ---------------------------------------------------------------------------
// Prep: blocks 0..511 = NCHW->NHWC bf16 transpose (one (b,h) row each);
//       blocks 512..727 = weight pack bf16 tap-major [o][tap][c].
// ---------------------------------------------------------------------------
__global__ __launch_bounds__(256) void prep_k(
    const float* __restrict__ x,  const float* __restrict__ ow,
    const float* __restrict__ dw, unsigned* __restrict__ xtb,
    short* __restrict__ owT,      short* __restrict__ dwT)
{
    int blk = blockIdx.x;
    int t = threadIdx.x;
    if (blk < 512) {
        int b = blk >> 7, h = blk & 127;
        __shared__ float sT[64 * 133];
        const float* xp = x + (size_t)b * Cn * HW + (size_t)h * Ww;
#pragma unroll
        for (int it = 0; it < 32; ++it) {
            int idx = t + 256 * it;        // c(6b) | w(7b)
            int c = idx >> 7, w = idx & 127;
            sT[c * 133 + w] = xp[(size_t)c * HW + w];
        }
        __syncthreads();
        unsigned* op = xtb + (size_t)blk * Ww * 32;   // 32 dwords (64 bf16)/px
#pragma unroll
        for (int it = 0; it < 16; ++it) {
            int idx = t + 256 * it;        // w(7b) | cp(5b)
            int w = idx >> 5, cp = idx & 31;
            unsigned lo = f2bf(sT[(2 * cp) * 133 + w]);
            unsigned hi = f2bf(sT[(2 * cp + 1) * 133 + w]);
            op[(size_t)w * 32 + cp] = lo | (hi << 16);
        }
    } else {
        int u = (blk - 512) * 4 + (t >> 6);   // 0..863
        int c = t & 63;
        if (u < 288) {
            int o = u / 9, kk = u % 9;
            float v = (o < 27) ? ow[(size_t)o * 576 + c * 9 + kk] : 0.0f;
            owT[(size_t)u * 64 + c] = (short)f2bf(v);
        } else {
            int u2 = u - 288;
            int o = u2 / 9, kk = u2 % 9;
            dwT[(size_t)u2 * 64 + c] = (short)f2bf(dw[(size_t)o * 576 + c * 9 + kk]);
        }
    }
}

// ---------------------------------------------------------------------------
// Fused: offset-conv GEMM -> per-thread bilinear prep -> sampling fill ->
// DCN GEMM -> conv store + BN stats partials (transposed part).
// R6: block = QUARTER-row (32 px), grid 2048, 256 threads / 4 waves.
// LDS ~15.7 KB -> 8 blocks/CU x 4 waves = 32 waves/CU (2x R4's TLP) with
// barrier epochs still 4-wave. R5's 8-wave/512-thread block REGRESSED
// (47->69 us, occupancy 37% not 100%): fat blocks convoy 8 waves per
// barrier and halve per-wave latency cover. TLP must come from MORE BLOCKS,
// not fatter blocks. VGPR must stay <=64 for 8 waves/SIMD (acc[2], oacc x1,
// fill unroll moderate).
// R3 lesson: barrier-free wave-private flip regressed (per-ks global B-frag
// loads on MFMA path). B streams 1-per-step from L1; A from LDS. DO NOT
// re-flip.
// CRITICAL #1: no __launch_bounds__ min-waves arg (R3 spill disaster).
// CRITICAL #2: wave id readfirstlane'd (R4 divergent-uniform trap).
// MFMA 16x16x32 bf16 (validated R8-R12):
//   A lane=[m=l15][k=quad*8+j]; B lane=[k=quad*8+j][n=l15];
//   D lane=[row=quad*4+r][col=l15].
// LDS: sA 12800 (sOMh 1860 aliased in) + prepQ 2304 + prepC 576 = 15680 B.
// ---------------------------------------------------------------------------
__global__ __launch_bounds__(256) void dcn_fused_k(
    const unsigned* __restrict__ xtb, const short* __restrict__ owT,
    const float* __restrict__ ob,     const short* __restrict__ dwT,
    float* __restrict__ conv,         float* __restrict__ part)
{
    int raw  = blockIdx.x;
    int blk  = ((raw & 7) << 8) | (raw >> 3);   // b(2b) | h(7b) | qtr(2b)
    int qtr  = blk & 3;
    int h    = (blk >> 2) & 127;
    int b    = blk >> 9;
    int px0  = qtr * 32;
    int t    = threadIdx.x;
    int lane = t & 63;
    int quad = lane >> 4;
    int l15  = lane & 15;
    int qw   = lane >> 4;          // quarter-wave unit id (phase 3 fill)
    int cl2  = lane & 15;          // dword-PAIR (4-channel) index, phase 3
    int og   = lane >> 3;          // eighth-wave unit id (phase 1 fill)
    int li   = lane & 7;           // dwordx4 lane, phase 1
    int w_s  = __builtin_amdgcn_readfirstlane(t >> 6);   // 0..3 (SGPR)

    __shared__ __align__(16) short sA[32 * KP];               // 12800 B (bf16)
    __shared__ __align__(16) unsigned short prepQ[288 * 4];   //  2304 B {idx,w00,w01,w10}
    __shared__ __align__(16) unsigned short prepC[288];       //   576 B {w11}
    short* sOMh = sA;   // 27*OMP+12 = 930 shorts, aliased (sA dead in phase 2)

    const unsigned* xbd = xtb + (size_t)b * HW * 32;               // dword view
    unsigned* sAd = (unsigned*)sA;                                 // row = 100 dw

    // ================= Phase 1: offset conv GEMM (M=32, N=32) ============
    // wave = (o-tile nt_o: 16 o) x (px-half mq: 16 px)
    int nt_o = w_s & 1;
    int mq   = w_s >> 1;
    int o_ow = nt_o * 16 + l15;
    f32x4 oacc = {0,0,0,0};

    for (int ck = 0; ck < 3; ++ck) {
        int yy = h + ck - 1;
        bool rowok = ((unsigned)yy < (unsigned)Hh);
        // ---- im2col fill: 96 units (kkl(2b)|px(5b)); 4 waves x 8 units x
        //      (8 lanes x dwordx4) -> 3 iters
#pragma unroll
        for (int it = 0; it < 3; ++it) {
            int unit = (it * 4 + w_s) * 8 + og;   // 0..95
            int kkl = unit >> 5, px = unit & 31;
            int xx = px0 + px + kkl - 1;
            bool valid = rowok && ((unsigned)xx < (unsigned)Ww);
            u32x4 v = {0u, 0u, 0u, 0u};
            if (valid)
                v = *(const u32x4*)&xbd[(((size_t)yy << 7) + xx) * 32 + li * 4];
            *(u32x4*)&sAd[px * 100 + kkl * 32 + li * 4] = v;
        }
        __syncthreads();
#pragma unroll
        for (int ks = 0; ks < 6; ++ks) {
            int kk = ck * 3 + (ks >> 1);
            bf16x8 bfr = *(const bf16x8*)&owT[((size_t)o_ow * 9 + kk) * 64
                                             + (ks & 1) * 32 + quad * 8];
            bf16x8 a = *(const bf16x8*)&sA[(mq * 16 + l15) * KP
                                           + ks * 32 + quad * 8];
            oacc = __builtin_amdgcn_mfma_f32_16x16x32_bf16(a, bfr, oacc, 0, 0, 0);
        }
        __syncthreads();
    }
    // ---- D -> sOMh (+bias), f16; px = mq*16 + quad*4 + r
    // (sA is dead here: last chunk's MFMAs completed before the final sync)
    if (o_ow < 27) {
        float bias = ob[o_ow];
        int pxb = mq * 16 + quad * 4;
#pragma unroll
        for (int r = 0; r < 4; ++r)
            sOMh[o_ow * OMP + pxb + r] = f2h(oacc[r] + bias);
    }
    __syncthreads();

    // ================= Phase 2: per-thread bilinear prep -> LDS ==========
    // 288 units = tap(9) x px(32); thread owns u = t (+256 for t<32).
    // Validity factorizes per-axis onto physical rows/cols (yb,yb+1)/(xb,xb+1);
    // corner weight = wr*wc, sigmoid mask folded into wr. Base idx yb*128+xb;
    // corners {+0,+1,+128,+129} always in-bounds.
#pragma unroll
    for (int i = 0; i < 2; ++i) {
        int u = t + 256 * i;
        if (u < 288) {
            int kk = u >> 5, px = u & 31;
            float ox = h2f((short)sOMh[kk * OMP + px]);
            float oy = h2f((short)sOMh[(9 + kk) * OMP + px]);
            float mr = h2f((short)sOMh[(18 + kk) * OMP + px]);
            float m  = 1.0f / (1.0f + __expf(-mr));
            float py  = (float)(h - 1 + (kk / 3)) + oy;
            float pxf = (float)(px0 + px - 1 + (kk % 3)) + ox;
            float y0f = floorf(py), x0f = floorf(pxf);
            int y0 = (int)y0f, x0 = (int)x0f;
            float wy = py - y0f, wx = pxf - x0f;
            int yb = min(max(y0, 0), Hh - 2);
            int xb = min(max(x0, 0), Ww - 2);
            float wr0 = (yb == y0) ? (1.0f - wy) : ((yb     == y0 + 1) ? wy : 0.0f);
            float wr1 = (yb == y0) ? wy          : ((yb + 1 == y0    ) ? (1.0f - wy) : 0.0f);
            float wc0 = (xb == x0) ? (1.0f - wx) : ((xb     == x0 + 1) ? wx : 0.0f);
            float wc1 = (xb == x0) ? wx          : ((xb + 1 == x0    ) ? (1.0f - wx) : 0.0f);
            wr0 *= m; wr1 *= m;
            prepQ[u * 4 + 0] = (unsigned short)(yb * Ww + xb);
            prepQ[u * 4 + 1] = (unsigned short)f2h(wr0 * wc0);
            prepQ[u * 4 + 2] = (unsigned short)f2h(wr0 * wc1);
            prepQ[u * 4 + 3] = (unsigned short)f2h(wr1 * wc0);
            prepC[u]         = (unsigned short)f2h(wr1 * wc1);
        }
    }
    __syncthreads();

    // ================= Phase 3: sampling fill + DCN GEMM (M=32, N=64) ====
    // wave = (o-tile w_s: 16 o) x all 32 px; acc[2].
    // Fill: 4 waves x 4 units (16 lanes each) = 16 units/iter -> 6 iters;
    // lane owns 4 CHANNELS (dword pair). Per unit: b64+b16 broadcast
    // ds_read, ONE gather addr chain, 4x dwordx2 (128B/corner coalesced),
    // 16 FMA, 2x v_cvt_pk_bf16_f32, 1 ds_write_b64.
    int o_dw = w_s * 16 + l15;
    f32x4 acc[2] = {{0,0,0,0},{0,0,0,0}};

    for (int ck = 0; ck < 3; ++ck) {
#pragma unroll 3
        for (int it = 0; it < 6; ++it) {
            int unit = (it * 4 + w_s) * 4 + qw;   // 0..95 within ck
            int kkl = unit >> 5, px = unit & 31;
            int uG = (ck * 3 + kkl) * 32 + px;    // global unit id, 0..287
            u16x4 q = *(const u16x4*)&prepQ[uG * 4];     // broadcast ds_read_b64
            float w00 = h2f((short)q[1]);
            float w01 = h2f((short)q[2]);
            float w10 = h2f((short)q[3]);
            float w11 = h2f((short)prepC[uG]);           // broadcast ds_read_u16
            const unsigned* p0 = xbd + (size_t)q[0] * 32 + cl2 * 2;
            u32x2 d00 = *(const u32x2*)(p0);
            u32x2 d01 = *(const u32x2*)(p0 + 32);        // col+1 (+128 B)
            u32x2 d10 = *(const u32x2*)(p0 + 4096);      // row+1
            u32x2 d11 = *(const u32x2*)(p0 + 4128);      // row+1, col+1
            u32x2 pkv;
#pragma unroll
            for (int j = 0; j < 2; ++j) {
                float v0 = w00 * bflo(d00[j]) + w01 * bflo(d01[j])
                         + w10 * bflo(d10[j]) + w11 * bflo(d11[j]);
                float v1 = w00 * bfhi(d00[j]) + w01 * bfhi(d01[j])
                         + w10 * bfhi(d10[j]) + w11 * bfhi(d11[j]);
                unsigned pk;
                asm("v_cvt_pk_bf16_f32 %0, %1, %2" : "=v"(pk) : "v"(v0), "v"(v1));
                pkv[j] = pk;
            }
            *(u32x2*)&sAd[px * 100 + kkl * 32 + cl2 * 2] = pkv;
        }
        __syncthreads();
#pragma unroll
        for (int ks = 0; ks < 6; ++ks) {
            int kk = ck * 3 + (ks >> 1);
            bf16x8 bfr = *(const bf16x8*)&dwT[((size_t)o_dw * 9 + kk) * 64
                                              + (ks & 1) * 32 + quad * 8];
#pragma unroll
            for (int mt = 0; mt < 2; ++mt) {
                bf16x8 a = *(const bf16x8*)&sA[(mt * 16 + l15) * KP
                                               + ks * 32 + quad * 8];
                acc[mt] = __builtin_amdgcn_mfma_f32_16x16x32_bf16(a, bfr, acc[mt], 0, 0, 0);
            }
        }
        __syncthreads();
    }

    // ================= Phase 4: store conv + stats partials =================
#pragma unroll
    for (int mt = 0; mt < 2; ++mt) {
        size_t idx = ((size_t)b * On + o_dw) * HW + (size_t)h * Ww
                   + px0 + mt * 16 + quad * 4;
        *(f32x4*)(conv + idx) = acc[mt];
    }
    // per-o sums over this block's 32 px (one wave owns each o) -> part[.][blk]
    float s1 = 0.0f, s2 = 0.0f;
#pragma unroll
    for (int mt = 0; mt < 2; ++mt) {
#pragma unroll
        for (int r = 0; r < 4; ++r) {
            float v = acc[mt][r];
            s1 += v;
            s2 += v * v;
        }
    }
    s1 += __shfl_down(s1, 32, 64);  s2 += __shfl_down(s2, 32, 64);
    s1 += __shfl_down(s1, 16, 64);  s2 += __shfl_down(s2, 16, 64);
    if (lane < 16) {
        part[(size_t)o_dw * NPART + blk]        = s1;
        part[(size_t)(64 + o_dw) * NPART + blk] = s2;
    }
}

// ---------------------------------------------------------------------------
// Fused BN stats + apply + ReLU.
// Grid 1024: o = idx&63, bq = idx>>6. Each block re-reduces its channel's
// part rows (16 KB, L2-hit) -> sc/sh, then applies BN+ReLU over a 4096-float
// slab of conv.
// ---------------------------------------------------------------------------
__global__ __launch_bounds__(256) void bnstats_k(
    const float* __restrict__ part, const float* __restrict__ gamma,
    const float* __restrict__ beta, const float* __restrict__ conv,
    float* __restrict__ out)
{
    int idx = blockIdx.x;
    int o  = idx & 63;
    int bq = idx >> 6;          // b = bq>>2, q = bq&3
    int t = threadIdx.x;
    float s1 = 0.0f, s2 = 0.0f;
#pragma unroll
    for (int i = 0; i < NPART / 256; ++i) {
        int j = t + 256 * i;
        s1 += part[(size_t)o * NPART + j];
        s2 += part[(size_t)(64 + o) * NPART + j];
    }
#pragma unroll
    for (int off = 32; off > 0; off >>= 1) {
        s1 += __shfl_down(s1, off, 64);
        s2 += __shfl_down(s2, off, 64);
    }
    __shared__ float r1[4], r2[4];
    __shared__ float sc_s, sh_s;
    if ((t & 63) == 0) { r1[t >> 6] = s1; r2[t >> 6] = s2; }
    __syncthreads();
    if (t == 0) {
        float S1 = r1[0] + r1[1] + r1[2] + r1[3];
        float S2 = r2[0] + r2[1] + r2[2] + r2[3];
        float n = (float)(Bn * HW);
        float mu = S1 / n;
        float var = S2 / n - mu * mu;
        float sc = gamma[o] * rsqrtf(var + 1e-5f);
        sc_s = sc;
        sh_s = beta[o] - mu * sc;
    }
    __syncthreads();
    float sc = sc_s, sh = sh_s;
    size_t base = (((size_t)(bq >> 2) * On + o) * HW + (size_t)(bq & 3) * 4096) / 4;
    const float4* cv = (const float4*)conv + base;
    float4* ov = (float4*)out + base;
#pragma unroll
    for (int i = 0; i < 4; ++i) {
        float4 v = cv[t + 256 * i];
        v.x = fmaxf(v.x * sc + sh, 0.0f);
        v.y = fmaxf(v.y * sc + sh, 0.0f);
        v.z = fmaxf(v.z * sc + sh, 0.0f);
        v.w = fmaxf(v.w * sc + sh, 0.0f);
        ov[t + 256 * i] = v;
    }
}

// ---------------------------------------------------------------------------
extern "C" void kernel_launch(void* const* d_in, const int* in_sizes, int n_in,
                              void* d_out, int out_size, void* d_ws, size_t ws_size,
                              hipStream_t stream)
{
    const float* x     = (const float*)d_in[0];
    const float* ow    = (const float*)d_in[1];
    const float* ob    = (const float*)d_in[2];
    const float* dw    = (const float*)d_in[3];
    // d_in[4] = dcn_b: cancels exactly under BN mean subtraction -> unused
    const float* gamma = (const float*)d_in[5];
    const float* beta  = (const float*)d_in[6];

    char* wsb = (char*)d_ws;
    unsigned* xtb = (unsigned*)wsb;
    float* conv = (float*)(wsb + XTB_BYTES);
    float* part = (float*)(wsb + XTB_BYTES + CONV_BYTES);
    short* owT  = (short*)(wsb + XTB_BYTES + CONV_BYTES + PART_BYTES + 512);
    short* dwT  = owT + 288 * 64;

    prep_k     <<<dim3(728),  dim3(256), 0, stream>>>(x, ow, dw, xtb, owT, dwT);
    dcn_fused_k<<<dim3(NBLK), dim3(256), 0, stream>>>(xtb, owT, ob, dwT, conv, part);
    bnstats_k  <<<dim3(1024), dim3(256), 0, stream>>>(part, gamma, beta, conv, (float*)d_out);
}

// Round 7
// 132.556 us; speedup vs baseline: 1.1381x; 1.0864x over previous
//
#include <hip/hip_runtime.h>
#include <math.h>

#define Hh 128
#define Ww 128
#define HW (Hh*Ww)
#define Bn 4
#define Cn 64
#define On 64
#define KP 200                // LDS A-row stride (shorts): 192 data + 8 pad
                              // (==0 mod 8 for 16B ds_read_b128; row stride
                              //  100 dw == 4 mod 32 banks -> 2-way max = free)
#define OMP 66                // padded px stride for sOM (f16), 64 px
#define NBLK 1024             // dcn grid (half-row blocks)

typedef __attribute__((ext_vector_type(8))) short bf16x8;
typedef __attribute__((ext_vector_type(4))) float f32x4;
typedef __attribute__((ext_vector_type(4))) unsigned short u16x4;
typedef __attribute__((ext_vector_type(2))) unsigned u32x2;
typedef __attribute__((ext_vector_type(4))) unsigned u32x4;

// fp32 -> bf16 round-to-nearest-even
static __device__ __forceinline__ unsigned short f2bf(float f) {
    unsigned u = __builtin_bit_cast(unsigned, f);
    u += 0x7FFFu + ((u >> 16) & 1u);
    return (unsigned short)(u >> 16);
}
static __device__ __forceinline__ short f2h(float f) {
    _Float16 h = (_Float16)f;
    return __builtin_bit_cast(short, h);
}
static __device__ __forceinline__ float h2f(short s) {
    return (float)__builtin_bit_cast(_Float16, s);
}
static __device__ __forceinline__ float bflo(unsigned d) {
    return __builtin_bit_cast(float, d << 16);
}
static __device__ __forceinline__ float bfhi(unsigned d) {
    return __builtin_bit_cast(float, d & 0xFFFF0000u);
}

// workspace layout (bytes): xtb(8M) | conv(16M) | part(512K) | ss | owT | dwT
#define XTB_BYTES   ((size_t)Bn*HW*64*2)
#define CONV_BYTES  ((size_t)Bn*On*HW*4)
#define PART_BYTES  ((size_t)128*NBLK*4)

// ---------------------------------------------------------------------------
// Prep: blocks 0..511 = NCHW->NHWC bf16 transpose (one (b,h) row each);
//       blocks 512..727 = weight pack bf16 tap-major [o][tap][c].
// ---------------------------------------------------------------------------
__global__ __launch_bounds__(256) void prep_k(
    const float* __restrict__ x,  const float* __restrict__ ow,
    const float* __restrict__ dw, unsigned* __restrict__ xtb,
    short* __restrict__ owT,      short* __restrict__ dwT)
{
    int blk = blockIdx.x;
    int t = threadIdx.x;
    if (blk < 512) {
        int b = blk >> 7, h = blk & 127;
        __shared__ float sT[64 * 133];
        const float* xp = x + (size_t)b * Cn * HW + (size_t)h * Ww;
#pragma unroll
        for (int it = 0; it < 32; ++it) {
            int idx = t + 256 * it;        // c(6b) | w(7b)
            int c = idx >> 7, w = idx & 127;
            sT[c * 133 + w] = xp[(size_t)c * HW + w];
        }
        __syncthreads();
        unsigned* op = xtb + (size_t)blk * Ww * 32;   // 32 dwords (64 bf16)/px
#pragma unroll
        for (int it = 0; it < 16; ++it) {
            int idx = t + 256 * it;        // w(7b) | cp(5b)
            int w = idx >> 5, cp = idx & 31;
            unsigned lo = f2bf(sT[(2 * cp) * 133 + w]);
            unsigned hi = f2bf(sT[(2 * cp + 1) * 133 + w]);
            op[(size_t)w * 32 + cp] = lo | (hi << 16);
        }
    } else {
        int u = (blk - 512) * 4 + (t >> 6);   // 0..863
        int c = t & 63;
        if (u < 288) {
            int o = u / 9, kk = u % 9;
            float v = (o < 27) ? ow[(size_t)o * 576 + c * 9 + kk] : 0.0f;
            owT[(size_t)u * 64 + c] = (short)f2bf(v);
        } else {
            int u2 = u - 288;
            int o = u2 / 9, kk = u2 % 9;
            dwT[(size_t)u2 * 64 + c] = (short)f2bf(dw[(size_t)o * 576 + c * 9 + kk]);
        }
    }
}

// ---------------------------------------------------------------------------
// Fused: offset-conv GEMM -> per-thread bilinear prep -> sampling fill ->
// DCN GEMM -> conv store + BN stats partials (transposed part).
// Block = HALF-row (64 px), grid 1024, 256 thr / 4 waves. x is bf16 NHWC.
// Structure = R2/R4. LESSONS LEDGER:
//  * R3: barrier-free wave-private flip REGRESSED (per-ks global B-frag
//    loads exposed L2 latency on MFMA path). B streams 1/step; A from LDS.
//  * R5 (8-wave block) & R6 (quarter-row, 2048 blocks): BOTH regressed to
//    ~67-69 us. Achieved residency is PINNED ~11-13 waves/CU regardless of
//    theoretical limits (16/32/32); halving per-wave work per barrier epoch
//    just doubles barrier-drain rate. Occupancy is NOT the lever; per-wave
//    ILP across barriers is. Keep half-row/4-wave/1024.
// R7 (this round): T14 issue-early/consume-late in phase 3. Prefetch the
// first 4 fill-units of ck+1 (16 dwordx2, ~48 VGPR state) BEFORE MFMA(ck);
// phase-3 barriers become raw s_barrier + explicit lgkmcnt(0) (m201
// pattern) so prefetched loads stay in flight across MFMA + both barriers
// (__syncthreads would vmcnt(0)-drain them). Consume right after the
// trailing barrier. Same arithmetic order -> bit-identical conv output.
// CRITICAL #1: no __launch_bounds__ min-waves arg (R3 spill disaster).
// CRITICAL #2: wave id readfirstlane'd (R4 divergent-uniform trap).
// CRITICAL #3: VGPR must stay <128 (4 waves/SIMD tier) -- prefetch depth
// chosen for ~110.
// MFMA 16x16x32 bf16 (validated R8-R12):
//   A lane=[m=l15][k=quad*8+j]; B lane=[k=quad*8+j][n=l15];
//   D lane=[row=quad*4+r][col=l15].
// LDS: sA 25600 (sOMh 3588 aliased in) + prepQ 4608 + prepC 1152 = 31360 B.
// ---------------------------------------------------------------------------
__global__ __launch_bounds__(256) void dcn_fused_k(
    const unsigned* __restrict__ xtb, const short* __restrict__ owT,
    const float* __restrict__ ob,     const short* __restrict__ dwT,
    float* __restrict__ conv,         float* __restrict__ part)
{
    int raw  = blockIdx.x;
    int blk  = ((raw & 7) << 7) | (raw >> 3);   // b(2b) | h(7b) | half(1b)
    int half = blk & 1;
    int h    = (blk >> 1) & 127;
    int b    = blk >> 8;
    int px0  = half * 64;
    int t    = threadIdx.x;
    int lane = t & 63;
    int quad = lane >> 4;
    int l15  = lane & 15;
    int qw   = lane >> 4;          // quarter-wave unit id (phase 3 fill)
    int cl2  = lane & 15;          // dword-PAIR (4-channel) index, phase 3
    int og   = lane >> 3;          // eighth-wave unit id (phase 1 fill)
    int li   = lane & 7;           // dwordx4 lane, phase 1
    int w_s  = __builtin_amdgcn_readfirstlane(t >> 6);   // 0..3 (SGPR)

    __shared__ __align__(16) short sA[64 * KP];               // 25600 B (bf16)
    __shared__ __align__(16) unsigned short prepQ[576 * 4];   //  4608 B {idx,w00,w01,w10}
    __shared__ __align__(16) unsigned short prepC[576];       //  1152 B {w11}
    short* sOMh = sA;   // 27*OMP+12 = 1794 shorts, aliased (sA dead in phase 2)

    const unsigned* xbd = xtb + (size_t)b * HW * 32;               // dword view
    unsigned* sAd = (unsigned*)sA;                                 // row = 100 dw

    // ================= Phase 1: offset conv GEMM (M=64, N=32) ============
    int nt_o = w_s & 1;
    int mh   = w_s >> 1;
    int o_ow = nt_o * 16 + l15;
    f32x4 oacc[2] = {{0,0,0,0},{0,0,0,0}};

    for (int ck = 0; ck < 3; ++ck) {
        int yy = h + ck - 1;
        bool rowok = ((unsigned)yy < (unsigned)Hh);
        // ---- im2col fill: 192 units (kkl(2b)|px(6b)), 8 lanes x dwordx4 each
#pragma unroll
        for (int it = 0; it < 6; ++it) {
            int unit = (it * 4 + w_s) * 8 + og;   // 0..191
            int kkl = unit >> 6, px = unit & 63;
            int xx = px0 + px + kkl - 1;
            bool valid = rowok && ((unsigned)xx < (unsigned)Ww);
            u32x4 v = {0u, 0u, 0u, 0u};
            if (valid)
                v = *(const u32x4*)&xbd[(((size_t)yy << 7) + xx) * 32 + li * 4];
            *(u32x4*)&sAd[px * 100 + kkl * 32 + li * 4] = v;
        }
        __syncthreads();
#pragma unroll
        for (int ks = 0; ks < 6; ++ks) {
            int kk = ck * 3 + (ks >> 1);
            bf16x8 bfr = *(const bf16x8*)&owT[((size_t)o_ow * 9 + kk) * 64
                                             + (ks & 1) * 32 + quad * 8];
#pragma unroll
            for (int m2 = 0; m2 < 2; ++m2) {
                bf16x8 a = *(const bf16x8*)&sA[(mh * 32 + m2 * 16 + l15) * KP
                                               + ks * 32 + quad * 8];
                oacc[m2] = __builtin_amdgcn_mfma_f32_16x16x32_bf16(a, bfr, oacc[m2], 0, 0, 0);
            }
        }
        __syncthreads();
    }
    // ---- D -> sOMh (+bias), f16; px = (mh*2+m2)*16 + quad*4 + r
    if (o_ow < 27) {
        float bias = ob[o_ow];
#pragma unroll
        for (int m2 = 0; m2 < 2; ++m2) {
            int pxb = (mh * 2 + m2) * 16 + quad * 4;
#pragma unroll
            for (int r = 0; r < 4; ++r)
                sOMh[o_ow * OMP + pxb + r] = f2h(oacc[m2][r] + bias);
        }
    }
    __syncthreads();

    // ================= Phase 2: per-thread bilinear prep -> LDS ==========
    // 576 units = tap(9) x px(64); thread owns u = t, t+256, t+512(<576).
    // Validity factorizes per-axis onto physical rows/cols (yb,yb+1)/(xb,xb+1);
    // corner weight = wr*wc, sigmoid mask folded into wr. Base idx yb*128+xb;
    // corners {+0,+1,+128,+129} always in-bounds.
#pragma unroll
    for (int i = 0; i < 3; ++i) {
        int u = t + 256 * i;
        if (u < 576) {
            int kk = u >> 6, px = u & 63;
            float ox = h2f((short)sOMh[kk * OMP + px]);
            float oy = h2f((short)sOMh[(9 + kk) * OMP + px]);
            float mr = h2f((short)sOMh[(18 + kk) * OMP + px]);
            float m  = 1.0f / (1.0f + __expf(-mr));
            float py  = (float)(h - 1 + (kk / 3)) + oy;
            float pxf = (float)(px0 + px - 1 + (kk % 3)) + ox;
            float y0f = floorf(py), x0f = floorf(pxf);
            int y0 = (int)y0f, x0 = (int)x0f;
            float wy = py - y0f, wx = pxf - x0f;
            int yb = min(max(y0, 0), Hh - 2);
            int xb = min(max(x0, 0), Ww - 2);
            float wr0 = (yb == y0) ? (1.0f - wy) : ((yb     == y0 + 1) ? wy : 0.0f);
            float wr1 = (yb == y0) ? wy          : ((yb + 1 == y0    ) ? (1.0f - wy) : 0.0f);
            float wc0 = (xb == x0) ? (1.0f - wx) : ((xb     == x0 + 1) ? wx : 0.0f);
            float wc1 = (xb == x0) ? wx          : ((xb + 1 == x0    ) ? (1.0f - wx) : 0.0f);
            wr0 *= m; wr1 *= m;
            prepQ[u * 4 + 0] = (unsigned short)(yb * Ww + xb);
            prepQ[u * 4 + 1] = (unsigned short)f2h(wr0 * wc0);
            prepQ[u * 4 + 2] = (unsigned short)f2h(wr0 * wc1);
            prepQ[u * 4 + 3] = (unsigned short)f2h(wr1 * wc0);
            prepC[u]         = (unsigned short)f2h(wr1 * wc1);
        }
    }
    __syncthreads();   // last full barrier; phase 3 uses raw barriers only

    // ================= Phase 3: sampling fill + DCN GEMM (M=64, N=64) ====
    // Fill: 4 units per wave-iter (quarter-waves); lane owns 4 CHANNELS
    // (dword pair). Iters 0..3 of each ck are PREFETCHED (loads issued
    // before the previous ck's MFMA; in flight across both raw barriers);
    // iters 4..11 run straight.
    int o_dw = w_s * 16 + l15;
    f32x4 acc[4] = {{0,0,0,0},{0,0,0,0},{0,0,0,0},{0,0,0,0}};

    // prefetch state: 4 units x 4 corners x dwordx2 + 4 weights
    u32x2 pd00[4], pd01[4], pd10[4], pd11[4];
    float pw00[4], pw01[4], pw10[4], pw11[4];

    // ---- initial prefetch: group-0 of ck=0 (units 0..63, kkl=0)
#pragma unroll
    for (int it = 0; it < 4; ++it) {
        int unit = (it * 4 + w_s) * 4 + qw;          // 0..63
        int uG = unit;                               // ck=0, kkl=0
        u16x4 q = *(const u16x4*)&prepQ[uG * 4];
        pw00[it] = h2f((short)q[1]);
        pw01[it] = h2f((short)q[2]);
        pw10[it] = h2f((short)q[3]);
        pw11[it] = h2f((short)prepC[uG]);
        const unsigned* p0 = xbd + (size_t)q[0] * 32 + cl2 * 2;
        pd00[it] = *(const u32x2*)(p0);
        pd01[it] = *(const u32x2*)(p0 + 32);
        pd10[it] = *(const u32x2*)(p0 + 4096);
        pd11[it] = *(const u32x2*)(p0 + 4128);
    }

    for (int ck = 0; ck < 3; ++ck) {
        // ---- consume prefetched group-0 (units 0..63 of this ck, kkl=0)
#pragma unroll
        for (int it = 0; it < 4; ++it) {
            int unit = (it * 4 + w_s) * 4 + qw;
            int px = unit & 63;                      // kkl = 0
            u32x2 pkv;
#pragma unroll
            for (int j = 0; j < 2; ++j) {
                float v0 = pw00[it] * bflo(pd00[it][j]) + pw01[it] * bflo(pd01[it][j])
                         + pw10[it] * bflo(pd10[it][j]) + pw11[it] * bflo(pd11[it][j]);
                float v1 = pw00[it] * bfhi(pd00[it][j]) + pw01[it] * bfhi(pd01[it][j])
                         + pw10[it] * bfhi(pd10[it][j]) + pw11[it] * bfhi(pd11[it][j]);
                unsigned pk;
                asm("v_cvt_pk_bf16_f32 %0, %1, %2" : "=v"(pk) : "v"(v0), "v"(v1));
                pkv[j] = pk;
            }
            *(u32x2*)&sAd[px * 100 + cl2 * 2] = pkv;
        }
        // ---- straight iters 4..11 (kkl 1..2)
#pragma unroll 4
        for (int it = 4; it < 12; ++it) {
            int unit = (it * 4 + w_s) * 4 + qw;      // 64..191
            int kkl = unit >> 6, px = unit & 63;
            int uG = ck * 192 + unit;
            u16x4 q = *(const u16x4*)&prepQ[uG * 4];     // broadcast ds_read_b64
            float w00 = h2f((short)q[1]);
            float w01 = h2f((short)q[2]);
            float w10 = h2f((short)q[3]);
            float w11 = h2f((short)prepC[uG]);           // broadcast ds_read_u16
            const unsigned* p0 = xbd + (size_t)q[0] * 32 + cl2 * 2;
            u32x2 d00 = *(const u32x2*)(p0);
            u32x2 d01 = *(const u32x2*)(p0 + 32);        // col+1 (+128 B)
            u32x2 d10 = *(const u32x2*)(p0 + 4096);      // row+1
            u32x2 d11 = *(const u32x2*)(p0 + 4128);      // row+1, col+1
            u32x2 pkv;
#pragma unroll
            for (int j = 0; j < 2; ++j) {
                float v0 = w00 * bflo(d00[j]) + w01 * bflo(d01[j])
                         + w10 * bflo(d10[j]) + w11 * bflo(d11[j]);
                float v1 = w00 * bfhi(d00[j]) + w01 * bfhi(d01[j])
                         + w10 * bfhi(d10[j]) + w11 * bfhi(d11[j]);
                unsigned pk;
                asm("v_cvt_pk_bf16_f32 %0, %1, %2" : "=v"(pk) : "v"(v0), "v"(v1));
                pkv[j] = pk;
            }
            *(u32x2*)&sAd[px * 100 + kkl * 32 + cl2 * 2] = pkv;
        }
        // ---- prefetch group-0 of NEXT ck: loads stay in flight across the
        //      raw barriers + MFMA below (T14 issue-early / consume-late)
        if (ck < 2) {
#pragma unroll
            for (int it = 0; it < 4; ++it) {
                int unit = (it * 4 + w_s) * 4 + qw;
                int uG = (ck + 1) * 192 + unit;      // kkl = 0
                u16x4 q = *(const u16x4*)&prepQ[uG * 4];
                pw00[it] = h2f((short)q[1]);
                pw01[it] = h2f((short)q[2]);
                pw10[it] = h2f((short)q[3]);
                pw11[it] = h2f((short)prepC[uG]);
                const unsigned* p0 = xbd + (size_t)q[0] * 32 + cl2 * 2;
                pd00[it] = *(const u32x2*)(p0);
                pd01[it] = *(const u32x2*)(p0 + 32);
                pd10[it] = *(const u32x2*)(p0 + 4096);
                pd11[it] = *(const u32x2*)(p0 + 4128);
            }
        }
        // ---- raw barrier: own ds_writes drained (lgkm), vmem NOT drained
        asm volatile("s_waitcnt lgkmcnt(0)" ::: "memory");
        __builtin_amdgcn_s_barrier();
#pragma unroll
        for (int ks = 0; ks < 6; ++ks) {
            int kk = ck * 3 + (ks >> 1);
            bf16x8 bfr = *(const bf16x8*)&dwT[((size_t)o_dw * 9 + kk) * 64
                                              + (ks & 1) * 32 + quad * 8];
#pragma unroll
            for (int mt = 0; mt < 4; ++mt) {
                bf16x8 a = *(const bf16x8*)&sA[(mt * 16 + l15) * KP
                                               + ks * 32 + quad * 8];
                acc[mt] = __builtin_amdgcn_mfma_f32_16x16x32_bf16(a, bfr, acc[mt], 0, 0, 0);
            }
        }
        // A-frag ds_reads are complete before each MFMA use (compiler waits),
        // so reaching this barrier implies this wave is done reading sA.
        __builtin_amdgcn_s_barrier();
    }

    // ================= Phase 4: store conv + stats partials =================
#pragma unroll
    for (int mt = 0; mt < 4; ++mt) {
        size_t idx = ((size_t)b * On + o_dw) * HW + (size_t)h * Ww + px0 + mt * 16 + quad * 4;
        *(f32x4*)(conv + idx) = acc[mt];
    }
    float s1 = 0.0f, s2 = 0.0f;
#pragma unroll
    for (int mt = 0; mt < 4; ++mt) {
#pragma unroll
        for (int r = 0; r < 4; ++r) {
            float v = acc[mt][r];
            s1 += v;
            s2 += v * v;
        }
    }
    s1 += __shfl_down(s1, 32, 64);  s2 += __shfl_down(s2, 32, 64);
    s1 += __shfl_down(s1, 16, 64);  s2 += __shfl_down(s2, 16, 64);
    if (lane < 16) {
        part[(size_t)o_dw * NBLK + blk]        = s1;
        part[(size_t)(64 + o_dw) * NBLK + blk] = s2;
    }
}

// ---------------------------------------------------------------------------
// Fused BN stats + apply + ReLU.
// Grid 1024: o = idx&63, bq = idx>>6. Each block re-reduces its channel's
// part rows (8 KB, L2-hit) -> sc/sh, then applies BN+ReLU over a 4096-float
// slab of conv.
// ---------------------------------------------------------------------------
__global__ __launch_bounds__(256) void bnstats_k(
    const float* __restrict__ part, const float* __restrict__ gamma,
    const float* __restrict__ beta, const float* __restrict__ conv,
    float* __restrict__ out)
{
    int idx = blockIdx.x;
    int o  = idx & 63;
    int bq = idx >> 6;          // b = bq>>2, q = bq&3
    int t = threadIdx.x;
    float s1 = 0.0f, s2 = 0.0f;
#pragma unroll
    for (int i = 0; i < NBLK / 256; ++i) {
        int j = t + 256 * i;
        s1 += part[(size_t)o * NBLK + j];
        s2 += part[(size_t)(64 + o) * NBLK + j];
    }
#pragma unroll
    for (int off = 32; off > 0; off >>= 1) {
        s1 += __shfl_down(s1, off, 64);
        s2 += __shfl_down(s2, off, 64);
    }
    __shared__ float r1[4], r2[4];
    __shared__ float sc_s, sh_s;
    if ((t & 63) == 0) { r1[t >> 6] = s1; r2[t >> 6] = s2; }
    __syncthreads();
    if (t == 0) {
        float S1 = r1[0] + r1[1] + r1[2] + r1[3];
        float S2 = r2[0] + r2[1] + r2[2] + r2[3];
        float n = (float)(Bn * HW);
        float mu = S1 / n;
        float var = S2 / n - mu * mu;
        float sc = gamma[o] * rsqrtf(var + 1e-5f);
        sc_s = sc;
        sh_s = beta[o] - mu * sc;
    }
    __syncthreads();
    float sc = sc_s, sh = sh_s;
    size_t base = (((size_t)(bq >> 2) * On + o) * HW + (size_t)(bq & 3) * 4096) / 4;
    const float4* cv = (const float4*)conv + base;
    float4* ov = (float4*)out + base;
#pragma unroll
    for (int i = 0; i < 4; ++i) {
        float4 v = cv[t + 256 * i];
        v.x = fmaxf(v.x * sc + sh, 0.0f);
        v.y = fmaxf(v.y * sc + sh, 0.0f);
        v.z = fmaxf(v.z * sc + sh, 0.0f);
        v.w = fmaxf(v.w * sc + sh, 0.0f);
        ov[t + 256 * i] = v;
    }
}

// ---------------------------------------------------------------------------
extern "C" void kernel_launch(void* const* d_in, const int* in_sizes, int n_in,
                              void* d_out, int out_size, void* d_ws, size_t ws_size,
                              hipStream_t stream)
{
    const float* x     = (const float*)d_in[0];
    const float* ow    = (const float*)d_in[1];
    const float* ob    = (const float*)d_in[2];
    const float* dw    = (const float*)d_in[3];
    // d_in[4] = dcn_b: cancels exactly under BN mean subtraction -> unused
    const float* gamma = (const float*)d_in[5];
    const float* beta  = (const float*)d_in[6];

    char* wsb = (char*)d_ws;
    unsigned* xtb = (unsigned*)wsb;
    float* conv = (float*)(wsb + XTB_BYTES);
    float* part = (float*)(wsb + XTB_BYTES + CONV_BYTES);
    short* owT  = (short*)(wsb + XTB_BYTES + CONV_BYTES + PART_BYTES + 512);
    short* dwT  = owT + 288 * 64;

    prep_k     <<<dim3(728),  dim3(256), 0, stream>>>(x, ow, dw, xtb, owT, dwT);
    dcn_fused_k<<<dim3(NBLK), dim3(256), 0, stream>>>(xtb, owT, ob, dwT, conv, part);
    bnstats_k  <<<dim3(1024), dim3(256), 0, stream>>>(part, gamma, beta, conv, (float*)d_out);
}

// Round 8
// 130.497 us; speedup vs baseline: 1.1561x; 1.0158x over previous
//
#include <hip/hip_runtime.h>
#include <math.h>

#define Hh 128
#define Ww 128
#define HW (Hh*Ww)
#define Bn 4
#define Cn 64
#define On 64
#define KP 200                // LDS A-row stride (shorts): 192 data + 8 pad
                              // (==0 mod 8 for 16B ds_read_b128; row stride
                              //  100 dw == 4 mod 32 banks -> 2-way max = free)
#define OMP 66                // padded px stride for sOM (f16), 64 px
#define NBLK 1024             // dcn grid (half-row blocks)

typedef __attribute__((ext_vector_type(8))) short bf16x8;
typedef __attribute__((ext_vector_type(4))) float f32x4;
typedef __attribute__((ext_vector_type(4))) unsigned short u16x4;
typedef __attribute__((ext_vector_type(2))) unsigned u32x2;
typedef __attribute__((ext_vector_type(4))) unsigned u32x4;

// fp32 -> bf16 round-to-nearest-even
static __device__ __forceinline__ unsigned short f2bf(float f) {
    unsigned u = __builtin_bit_cast(unsigned, f);
    u += 0x7FFFu + ((u >> 16) & 1u);
    return (unsigned short)(u >> 16);
}
static __device__ __forceinline__ short f2h(float f) {
    _Float16 h = (_Float16)f;
    return __builtin_bit_cast(short, h);
}
static __device__ __forceinline__ float h2f(short s) {
    return (float)__builtin_bit_cast(_Float16, s);
}
static __device__ __forceinline__ float bflo(unsigned d) {
    return __builtin_bit_cast(float, d << 16);
}
static __device__ __forceinline__ float bfhi(unsigned d) {
    return __builtin_bit_cast(float, d & 0xFFFF0000u);
}

// workspace layout (bytes): xtb(8M) | conv(16M) | part(512K) | ss | owT | dwT
#define XTB_BYTES   ((size_t)Bn*HW*64*2)
#define CONV_BYTES  ((size_t)Bn*On*HW*4)
#define PART_BYTES  ((size_t)128*NBLK*4)

// ---------------------------------------------------------------------------
// Prep: blocks 0..511 = NCHW->NHWC bf16 transpose (one (b,h) row each);
//       blocks 512..727 = weight pack bf16 tap-major [o][tap][c].
// ---------------------------------------------------------------------------
__global__ __launch_bounds__(256) void prep_k(
    const float* __restrict__ x,  const float* __restrict__ ow,
    const float* __restrict__ dw, unsigned* __restrict__ xtb,
    short* __restrict__ owT,      short* __restrict__ dwT)
{
    int blk = blockIdx.x;
    int t = threadIdx.x;
    if (blk < 512) {
        int b = blk >> 7, h = blk & 127;
        __shared__ float sT[64 * 133];
        const float* xp = x + (size_t)b * Cn * HW + (size_t)h * Ww;
#pragma unroll
        for (int it = 0; it < 32; ++it) {
            int idx = t + 256 * it;        // c(6b) | w(7b)
            int c = idx >> 7, w = idx & 127;
            sT[c * 133 + w] = xp[(size_t)c * HW + w];
        }
        __syncthreads();
        unsigned* op = xtb + (size_t)blk * Ww * 32;   // 32 dwords (64 bf16)/px
#pragma unroll
        for (int it = 0; it < 16; ++it) {
            int idx = t + 256 * it;        // w(7b) | cp(5b)
            int w = idx >> 5, cp = idx & 31;
            unsigned lo = f2bf(sT[(2 * cp) * 133 + w]);
            unsigned hi = f2bf(sT[(2 * cp + 1) * 133 + w]);
            op[(size_t)w * 32 + cp] = lo | (hi << 16);
        }
    } else {
        int u = (blk - 512) * 4 + (t >> 6);   // 0..863
        int c = t & 63;
        if (u < 288) {
            int o = u / 9, kk = u % 9;
            float v = (o < 27) ? ow[(size_t)o * 576 + c * 9 + kk] : 0.0f;
            owT[(size_t)u * 64 + c] = (short)f2bf(v);
        } else {
            int u2 = u - 288;
            int o = u2 / 9, kk = u2 % 9;
            dwT[(size_t)u2 * 64 + c] = (short)f2bf(dw[(size_t)o * 576 + c * 9 + kk]);
        }
    }
}

// ---------------------------------------------------------------------------
// Fused: offset-conv GEMM -> per-thread bilinear prep -> sampling fill ->
// DCN GEMM -> conv store + BN stats partials (transposed part).
// Block = HALF-row (64 px), grid 1024, 256 thr / 4 waves. x is bf16 NHWC.
// Structure = R2/R4. LESSONS LEDGER:
//  * R3: barrier-free wave-private flip REGRESSED (per-ks global B-frag
//    loads exposed L2 latency on MFMA path). B streams 1/step; A from LDS.
//  * R5 (8-wave block) & R6 (quarter-row/2048 blocks): BOTH ~67-69 us.
//    Achieved residency pinned ~11-13 waves/CU regardless of theoretical
//    cap; occupancy is NOT the lever. Keep half-row/4-wave/1024.
//  * R7: cross-barrier prefetch in plain C was SUNK by the compiler to the
//    consume site (VGPR stayed 60) -- s_barrier does not pin pure loads.
//    Raw-barrier scaffolding reverted.
// R8 (this round): IN-LOOP register double-buffer in the phase-3 fill.
// 12 iters -> 6 groups of 2, fully unrolled, 3 static buffer slots;
// ISSUE(g+2) precedes CONSUME(g) in program order (no barrier between, so
// the scheduler's natural load-hoisting keeps ~16 loads in flight across
// group boundaries -- the overlap unroll-4 could not express). Same
// per-unit arithmetic order -> bit-identical conv output.
// CRITICAL #1: no __launch_bounds__ min-waves arg (R3 spill disaster).
// CRITICAL #2: wave id readfirstlane'd (R4 divergent-uniform trap).
// CRITICAL #3: VGPR must stay <128 (watch: ~60 means pipeline defeated,
// >=128 means tier loss).
// MFMA 16x16x32 bf16 (validated R8-R12):
//   A lane=[m=l15][k=quad*8+j]; B lane=[k=quad*8+j][n=l15];
//   D lane=[row=quad*4+r][col=l15].
// LDS: sA 25600 (sOMh 3588 aliased in) + prepQ 4608 + prepC 1152 = 31360 B.
// ---------------------------------------------------------------------------
__global__ __launch_bounds__(256) void dcn_fused_k(
    const unsigned* __restrict__ xtb, const short* __restrict__ owT,
    const float* __restrict__ ob,     const short* __restrict__ dwT,
    float* __restrict__ conv,         float* __restrict__ part)
{
    int raw  = blockIdx.x;
    int blk  = ((raw & 7) << 7) | (raw >> 3);   // b(2b) | h(7b) | half(1b)
    int half = blk & 1;
    int h    = (blk >> 1) & 127;
    int b    = blk >> 8;
    int px0  = half * 64;
    int t    = threadIdx.x;
    int lane = t & 63;
    int quad = lane >> 4;
    int l15  = lane & 15;
    int qw   = lane >> 4;          // quarter-wave unit id (phase 3 fill)
    int cl2  = lane & 15;          // dword-PAIR (4-channel) index, phase 3
    int og   = lane >> 3;          // eighth-wave unit id (phase 1 fill)
    int li   = lane & 7;           // dwordx4 lane, phase 1
    int w_s  = __builtin_amdgcn_readfirstlane(t >> 6);   // 0..3 (SGPR)

    __shared__ __align__(16) short sA[64 * KP];               // 25600 B (bf16)
    __shared__ __align__(16) unsigned short prepQ[576 * 4];   //  4608 B {idx,w00,w01,w10}
    __shared__ __align__(16) unsigned short prepC[576];       //  1152 B {w11}
    short* sOMh = sA;   // 27*OMP+12 = 1794 shorts, aliased (sA dead in phase 2)

    const unsigned* xbd = xtb + (size_t)b * HW * 32;               // dword view
    unsigned* sAd = (unsigned*)sA;                                 // row = 100 dw

    // ================= Phase 1: offset conv GEMM (M=64, N=32) ============
    int nt_o = w_s & 1;
    int mh   = w_s >> 1;
    int o_ow = nt_o * 16 + l15;
    f32x4 oacc[2] = {{0,0,0,0},{0,0,0,0}};

    for (int ck = 0; ck < 3; ++ck) {
        int yy = h + ck - 1;
        bool rowok = ((unsigned)yy < (unsigned)Hh);
        // ---- im2col fill: 192 units (kkl(2b)|px(6b)), 8 lanes x dwordx4 each
#pragma unroll
        for (int it = 0; it < 6; ++it) {
            int unit = (it * 4 + w_s) * 8 + og;   // 0..191
            int kkl = unit >> 6, px = unit & 63;
            int xx = px0 + px + kkl - 1;
            bool valid = rowok && ((unsigned)xx < (unsigned)Ww);
            u32x4 v = {0u, 0u, 0u, 0u};
            if (valid)
                v = *(const u32x4*)&xbd[(((size_t)yy << 7) + xx) * 32 + li * 4];
            *(u32x4*)&sAd[px * 100 + kkl * 32 + li * 4] = v;
        }
        __syncthreads();
#pragma unroll
        for (int ks = 0; ks < 6; ++ks) {
            int kk = ck * 3 + (ks >> 1);
            bf16x8 bfr = *(const bf16x8*)&owT[((size_t)o_ow * 9 + kk) * 64
                                             + (ks & 1) * 32 + quad * 8];
#pragma unroll
            for (int m2 = 0; m2 < 2; ++m2) {
                bf16x8 a = *(const bf16x8*)&sA[(mh * 32 + m2 * 16 + l15) * KP
                                               + ks * 32 + quad * 8];
                oacc[m2] = __builtin_amdgcn_mfma_f32_16x16x32_bf16(a, bfr, oacc[m2], 0, 0, 0);
            }
        }
        __syncthreads();
    }
    // ---- D -> sOMh (+bias), f16; px = (mh*2+m2)*16 + quad*4 + r
    if (o_ow < 27) {
        float bias = ob[o_ow];
#pragma unroll
        for (int m2 = 0; m2 < 2; ++m2) {
            int pxb = (mh * 2 + m2) * 16 + quad * 4;
#pragma unroll
            for (int r = 0; r < 4; ++r)
                sOMh[o_ow * OMP + pxb + r] = f2h(oacc[m2][r] + bias);
        }
    }
    __syncthreads();

    // ================= Phase 2: per-thread bilinear prep -> LDS ==========
    // 576 units = tap(9) x px(64); thread owns u = t, t+256, t+512(<576).
    // Validity factorizes per-axis onto physical rows/cols (yb,yb+1)/(xb,xb+1);
    // corner weight = wr*wc, sigmoid mask folded into wr. Base idx yb*128+xb;
    // corners {+0,+1,+128,+129} always in-bounds.
#pragma unroll
    for (int i = 0; i < 3; ++i) {
        int u = t + 256 * i;
        if (u < 576) {
            int kk = u >> 6, px = u & 63;
            float ox = h2f((short)sOMh[kk * OMP + px]);
            float oy = h2f((short)sOMh[(9 + kk) * OMP + px]);
            float mr = h2f((short)sOMh[(18 + kk) * OMP + px]);
            float m  = 1.0f / (1.0f + __expf(-mr));
            float py  = (float)(h - 1 + (kk / 3)) + oy;
            float pxf = (float)(px0 + px - 1 + (kk % 3)) + ox;
            float y0f = floorf(py), x0f = floorf(pxf);
            int y0 = (int)y0f, x0 = (int)x0f;
            float wy = py - y0f, wx = pxf - x0f;
            int yb = min(max(y0, 0), Hh - 2);
            int xb = min(max(x0, 0), Ww - 2);
            float wr0 = (yb == y0) ? (1.0f - wy) : ((yb     == y0 + 1) ? wy : 0.0f);
            float wr1 = (yb == y0) ? wy          : ((yb + 1 == y0    ) ? (1.0f - wy) : 0.0f);
            float wc0 = (xb == x0) ? (1.0f - wx) : ((xb     == x0 + 1) ? wx : 0.0f);
            float wc1 = (xb == x0) ? wx          : ((xb + 1 == x0    ) ? (1.0f - wx) : 0.0f);
            wr0 *= m; wr1 *= m;
            prepQ[u * 4 + 0] = (unsigned short)(yb * Ww + xb);
            prepQ[u * 4 + 1] = (unsigned short)f2h(wr0 * wc0);
            prepQ[u * 4 + 2] = (unsigned short)f2h(wr0 * wc1);
            prepQ[u * 4 + 3] = (unsigned short)f2h(wr1 * wc0);
            prepC[u]         = (unsigned short)f2h(wr1 * wc1);
        }
    }
    __syncthreads();

    // ================= Phase 3: sampling fill + DCN GEMM (M=64, N=64) ====
    // Fill: 12 iters = 6 groups of 2, depth-2 register double-buffer
    // (3 slots). ISSUE(g) reads prepQ/prepC and launches 8 dwordx2 gathers
    // into slot s; CONSUME(g) does the bilinear FMAs + cvt_pk + ds_write.
    // Program order per group g: ISSUE(g+2) ; CONSUME(g) -- two groups of
    // loads in flight cover the ~250cy L2 latency with ~320cy of VALU.
    int o_dw = w_s * 16 + l15;
    f32x4 acc[4] = {{0,0,0,0},{0,0,0,0},{0,0,0,0},{0,0,0,0}};

    u32x2 dbuf[3][2][4];
    u16x4 qbuf[3][2];
    unsigned short cbuf[3][2];

#define P3_ISSUE(g, s) {                                                     \
    _Pragma("unroll")                                                        \
    for (int i = 0; i < 2; ++i) {                                            \
        int unit = (((g) * 2 + i) * 4 + w_s) * 4 + qw;                       \
        int uG = ck * 192 + unit;                                            \
        qbuf[s][i] = *(const u16x4*)&prepQ[uG * 4];                          \
        cbuf[s][i] = prepC[uG];                                              \
        const unsigned* p0 = xbd + (size_t)qbuf[s][i][0] * 32 + cl2 * 2;     \
        dbuf[s][i][0] = *(const u32x2*)(p0);                                 \
        dbuf[s][i][1] = *(const u32x2*)(p0 + 32);                            \
        dbuf[s][i][2] = *(const u32x2*)(p0 + 4096);                          \
        dbuf[s][i][3] = *(const u32x2*)(p0 + 4128);                          \
    } }

#define P3_CONSUME(g, s) {                                                   \
    _Pragma("unroll")                                                        \
    for (int i = 0; i < 2; ++i) {                                            \
        int unit = (((g) * 2 + i) * 4 + w_s) * 4 + qw;                       \
        int kkl = unit >> 6, px = unit & 63;                                 \
        float w00 = h2f((short)qbuf[s][i][1]);                               \
        float w01 = h2f((short)qbuf[s][i][2]);                               \
        float w10 = h2f((short)qbuf[s][i][3]);                               \
        float w11 = h2f((short)cbuf[s][i]);                                  \
        u32x2 pkv;                                                           \
        _Pragma("unroll")                                                    \
        for (int j = 0; j < 2; ++j) {                                        \
            float v0 = w00 * bflo(dbuf[s][i][0][j]) + w01 * bflo(dbuf[s][i][1][j]) \
                     + w10 * bflo(dbuf[s][i][2][j]) + w11 * bflo(dbuf[s][i][3][j]); \
            float v1 = w00 * bfhi(dbuf[s][i][0][j]) + w01 * bfhi(dbuf[s][i][1][j]) \
                     + w10 * bfhi(dbuf[s][i][2][j]) + w11 * bfhi(dbuf[s][i][3][j]); \
            unsigned pk;                                                     \
            asm("v_cvt_pk_bf16_f32 %0, %1, %2" : "=v"(pk) : "v"(v0), "v"(v1)); \
            pkv[j] = pk;                                                     \
        }                                                                    \
        *(u32x2*)&sAd[px * 100 + kkl * 32 + cl2 * 2] = pkv;                  \
    } }

    for (int ck = 0; ck < 3; ++ck) {
        P3_ISSUE(0, 0);
        P3_ISSUE(1, 1);
#pragma unroll
        for (int g = 0; g < 6; ++g) {
            if (g + 2 < 6) {
                switch ((g + 2) % 3) {
                    case 0: P3_ISSUE(g + 2, 0); break;
                    case 1: P3_ISSUE(g + 2, 1); break;
                    default: P3_ISSUE(g + 2, 2); break;
                }
            }
            switch (g % 3) {
                case 0: P3_CONSUME(g, 0); break;
                case 1: P3_CONSUME(g, 1); break;
                default: P3_CONSUME(g, 2); break;
            }
        }
        __syncthreads();
#pragma unroll
        for (int ks = 0; ks < 6; ++ks) {
            int kk = ck * 3 + (ks >> 1);
            bf16x8 bfr = *(const bf16x8*)&dwT[((size_t)o_dw * 9 + kk) * 64
                                              + (ks & 1) * 32 + quad * 8];
#pragma unroll
            for (int mt = 0; mt < 4; ++mt) {
                bf16x8 a = *(const bf16x8*)&sA[(mt * 16 + l15) * KP
                                               + ks * 32 + quad * 8];
                acc[mt] = __builtin_amdgcn_mfma_f32_16x16x32_bf16(a, bfr, acc[mt], 0, 0, 0);
            }
        }
        __syncthreads();
    }
#undef P3_ISSUE
#undef P3_CONSUME

    // ================= Phase 4: store conv + stats partials =================
#pragma unroll
    for (int mt = 0; mt < 4; ++mt) {
        size_t idx = ((size_t)b * On + o_dw) * HW + (size_t)h * Ww + px0 + mt * 16 + quad * 4;
        *(f32x4*)(conv + idx) = acc[mt];
    }
    float s1 = 0.0f, s2 = 0.0f;
#pragma unroll
    for (int mt = 0; mt < 4; ++mt) {
#pragma unroll
        for (int r = 0; r < 4; ++r) {
            float v = acc[mt][r];
            s1 += v;
            s2 += v * v;
        }
    }
    s1 += __shfl_down(s1, 32, 64);  s2 += __shfl_down(s2, 32, 64);
    s1 += __shfl_down(s1, 16, 64);  s2 += __shfl_down(s2, 16, 64);
    if (lane < 16) {
        part[(size_t)o_dw * NBLK + blk]        = s1;
        part[(size_t)(64 + o_dw) * NBLK + blk] = s2;
    }
}

// ---------------------------------------------------------------------------
// Fused BN stats + apply + ReLU.
// Grid 1024: o = idx&63, bq = idx>>6. Each block re-reduces its channel's
// part rows (8 KB, L2-hit) -> sc/sh, then applies BN+ReLU over a 4096-float
// slab of conv.
// ---------------------------------------------------------------------------
__global__ __launch_bounds__(256) void bnstats_k(
    const float* __restrict__ part, const float* __restrict__ gamma,
    const float* __restrict__ beta, const float* __restrict__ conv,
    float* __restrict__ out)
{
    int idx = blockIdx.x;
    int o  = idx & 63;
    int bq = idx >> 6;          // b = bq>>2, q = bq&3
    int t = threadIdx.x;
    float s1 = 0.0f, s2 = 0.0f;
#pragma unroll
    for (int i = 0; i < NBLK / 256; ++i) {
        int j = t + 256 * i;
        s1 += part[(size_t)o * NBLK + j];
        s2 += part[(size_t)(64 + o) * NBLK + j];
    }
#pragma unroll
    for (int off = 32; off > 0; off >>= 1) {
        s1 += __shfl_down(s1, off, 64);
        s2 += __shfl_down(s2, off, 64);
    }
    __shared__ float r1[4], r2[4];
    __shared__ float sc_s, sh_s;
    if ((t & 63) == 0) { r1[t >> 6] = s1; r2[t >> 6] = s2; }
    __syncthreads();
    if (t == 0) {
        float S1 = r1[0] + r1[1] + r1[2] + r1[3];
        float S2 = r2[0] + r2[1] + r2[2] + r2[3];
        float n = (float)(Bn * HW);
        float mu = S1 / n;
        float var = S2 / n - mu * mu;
        float sc = gamma[o] * rsqrtf(var + 1e-5f);
        sc_s = sc;
        sh_s = beta[o] - mu * sc;
    }
    __syncthreads();
    float sc = sc_s, sh = sh_s;
    size_t base = (((size_t)(bq >> 2) * On + o) * HW + (size_t)(bq & 3) * 4096) / 4;
    const float4* cv = (const float4*)conv + base;
    float4* ov = (float4*)out + base;
#pragma unroll
    for (int i = 0; i < 4; ++i) {
        float4 v = cv[t + 256 * i];
        v.x = fmaxf(v.x * sc + sh, 0.0f);
        v.y = fmaxf(v.y * sc + sh, 0.0f);
        v.z = fmaxf(v.z * sc + sh, 0.0f);
        v.w = fmaxf(v.w * sc + sh, 0.0f);
        ov[t + 256 * i] = v;
    }
}

// ---------------------------------------------------------------------------
extern "C" void kernel_launch(void* const* d_in, const int* in_sizes, int n_in,
                              void* d_out, int out_size, void* d_ws, size_t ws_size,
                              hipStream_t stream)
{
    const float* x     = (const float*)d_in[0];
    const float* ow    = (const float*)d_in[1];
    const float* ob    = (const float*)d_in[2];
    const float* dw    = (const float*)d_in[3];
    // d_in[4] = dcn_b: cancels exactly under BN mean subtraction -> unused
    const float* gamma = (const float*)d_in[5];
    const float* beta  = (const float*)d_in[6];

    char* wsb = (char*)d_ws;
    unsigned* xtb = (unsigned*)wsb;
    float* conv = (float*)(wsb + XTB_BYTES);
    float* part = (float*)(wsb + XTB_BYTES + CONV_BYTES);
    short* owT  = (short*)(wsb + XTB_BYTES + CONV_BYTES + PART_BYTES + 512);
    short* dwT  = owT + 288 * 64;

    prep_k     <<<dim3(728),  dim3(256), 0, stream>>>(x, ow, dw, xtb, owT, dwT);
    dcn_fused_k<<<dim3(NBLK), dim3(256), 0, stream>>>(xtb, owT, ob, dwT, conv, part);
    bnstats_k  <<<dim3(1024), dim3(256), 0, stream>>>(part, gamma, beta, conv, (float*)d_out);
}

// Round 9
// 128.703 us; speedup vs baseline: 1.1722x; 1.0139x over previous
//
#include <hip/hip_runtime.h>
#include <math.h>

#define Hh 128
#define Ww 128
#define HW (Hh*Ww)
#define Bn 4
#define Cn 64
#define On 64
#define KP 200                // LDS A-row stride (shorts): 192 data + 8 pad
                              // (==0 mod 8 for 16B ds_read_b128; row stride
                              //  100 dw == 4 mod 32 banks -> 2-way max = free)
#define OMP 66                // padded px stride for sOM (f16), 64 px
#define NBLK 1024             // dcn grid (half-row blocks)

typedef __attribute__((ext_vector_type(8))) short bf16x8;
typedef __attribute__((ext_vector_type(4))) float f32x4;
typedef __attribute__((ext_vector_type(4))) unsigned short u16x4;
typedef __attribute__((ext_vector_type(4))) unsigned u32x4;

// fp32 -> bf16 round-to-nearest-even
static __device__ __forceinline__ unsigned short f2bf(float f) {
    unsigned u = __builtin_bit_cast(unsigned, f);
    u += 0x7FFFu + ((u >> 16) & 1u);
    return (unsigned short)(u >> 16);
}
static __device__ __forceinline__ short f2h(float f) {
    _Float16 h = (_Float16)f;
    return __builtin_bit_cast(short, h);
}
static __device__ __forceinline__ float h2f(short s) {
    return (float)__builtin_bit_cast(_Float16, s);
}
static __device__ __forceinline__ float bflo(unsigned d) {
    return __builtin_bit_cast(float, d << 16);
}
static __device__ __forceinline__ float bfhi(unsigned d) {
    return __builtin_bit_cast(float, d & 0xFFFF0000u);
}

// workspace layout (bytes): xtb(8M) | conv(16M) | part(512K) | ss | owT | dwT
#define XTB_BYTES   ((size_t)Bn*HW*64*2)
#define CONV_BYTES  ((size_t)Bn*On*HW*4)
#define PART_BYTES  ((size_t)128*NBLK*4)

// ---------------------------------------------------------------------------
// Prep: blocks 0..511 = NCHW->NHWC bf16 transpose (one (b,h) row each);
//       blocks 512..727 = weight pack bf16 tap-major [o][tap][c].
// ---------------------------------------------------------------------------
__global__ __launch_bounds__(256) void prep_k(
    const float* __restrict__ x,  const float* __restrict__ ow,
    const float* __restrict__ dw, unsigned* __restrict__ xtb,
    short* __restrict__ owT,      short* __restrict__ dwT)
{
    int blk = blockIdx.x;
    int t = threadIdx.x;
    if (blk < 512) {
        int b = blk >> 7, h = blk & 127;
        __shared__ float sT[64 * 133];
        const float* xp = x + (size_t)b * Cn * HW + (size_t)h * Ww;
#pragma unroll
        for (int it = 0; it < 32; ++it) {
            int idx = t + 256 * it;        // c(6b) | w(7b)
            int c = idx >> 7, w = idx & 127;
            sT[c * 133 + w] = xp[(size_t)c * HW + w];
        }
        __syncthreads();
        unsigned* op = xtb + (size_t)blk * Ww * 32;   // 32 dwords (64 bf16)/px
#pragma unroll
        for (int it = 0; it < 16; ++it) {
            int idx = t + 256 * it;        // w(7b) | cp(5b)
            int w = idx >> 5, cp = idx & 31;
            unsigned lo = f2bf(sT[(2 * cp) * 133 + w]);
            unsigned hi = f2bf(sT[(2 * cp + 1) * 133 + w]);
            op[(size_t)w * 32 + cp] = lo | (hi << 16);
        }
    } else {
        int u = (blk - 512) * 4 + (t >> 6);   // 0..863
        int c = t & 63;
        if (u < 288) {
            int o = u / 9, kk = u % 9;
            float v = (o < 27) ? ow[(size_t)o * 576 + c * 9 + kk] : 0.0f;
            owT[(size_t)u * 64 + c] = (short)f2bf(v);
        } else {
            int u2 = u - 288;
            int o = u2 / 9, kk = u2 % 9;
            dwT[(size_t)u2 * 64 + c] = (short)f2bf(dw[(size_t)o * 576 + c * 9 + kk]);
        }
    }
}

// ---------------------------------------------------------------------------
// Fused: offset-conv GEMM -> per-thread bilinear prep -> sampling fill ->
// DCN GEMM -> conv store + BN stats partials (transposed part).
// Block = HALF-row (64 px), grid 1024, 256 thr / 4 waves. x is bf16 NHWC.
// Structure = R2/R4. LESSONS LEDGER:
//  * R3: barrier-free wave-private flip REGRESSED (per-ks global B-frag
//    loads exposed L2 latency on MFMA path). B streams 1/step; A from LDS.
//  * R5 (8-wave block) & R6 (quarter-row/2048 blocks): BOTH ~67-69 us.
//    Achieved residency pinned ~11-13 waves/CU regardless of theoretical
//    cap; occupancy is NOT the lever. Keep half-row/4-wave/1024.
//  * R7 (cross-barrier prefetch) & R8 (register double-buffer): BOTH
//    defeated -- LLVM sinks pure VMEM loads to their use site (VGPR stayed
//    60 both times). Source-level scheduling does not stick on this kernel.
//    The ONLY lever that pays is fewer VMEM/issue events (R1, R4).
// R9 (this round): gather width dwordx2 -> dwordx4 (8 channels per lane,
// the max). 8 lanes/unit; fill iters 12 -> 6; VMEM instr/wave/ck 48 -> 24;
// addr chains, prepQ reads, loop overhead halve; FMA count unchanged.
// Same per-channel arithmetic order -> bit-identical conv output.
// CRITICAL #1: no __launch_bounds__ min-waves arg (R3 spill disaster).
// CRITICAL #2: wave id readfirstlane'd (R4 divergent-uniform trap).
// MFMA 16x16x32 bf16 (validated R8-R12):
//   A lane=[m=l15][k=quad*8+j]; B lane=[k=quad*8+j][n=l15];
//   D lane=[row=quad*4+r][col=l15].
// LDS: sA 25600 (sOMh 3588 aliased in) + prepQ 4608 + prepC 1152 = 31360 B.
// ---------------------------------------------------------------------------
__global__ __launch_bounds__(256) void dcn_fused_k(
    const unsigned* __restrict__ xtb, const short* __restrict__ owT,
    const float* __restrict__ ob,     const short* __restrict__ dwT,
    float* __restrict__ conv,         float* __restrict__ part)
{
    int raw  = blockIdx.x;
    int blk  = ((raw & 7) << 7) | (raw >> 3);   // b(2b) | h(7b) | half(1b)
    int half = blk & 1;
    int h    = (blk >> 1) & 127;
    int b    = blk >> 8;
    int px0  = half * 64;
    int t    = threadIdx.x;
    int lane = t & 63;
    int quad = lane >> 4;
    int l15  = lane & 15;
    int ul   = lane >> 3;          // eighth-wave unit id (phase 3 fill, 0..7)
    int cl3  = lane & 7;           // dwordx4 (8-channel) group, phase 3
    int og   = lane >> 3;          // eighth-wave unit id (phase 1 fill)
    int li   = lane & 7;           // dwordx4 lane, phase 1
    int w_s  = __builtin_amdgcn_readfirstlane(t >> 6);   // 0..3 (SGPR)

    __shared__ __align__(16) short sA[64 * KP];               // 25600 B (bf16)
    __shared__ __align__(16) unsigned short prepQ[576 * 4];   //  4608 B {idx,w00,w01,w10}
    __shared__ __align__(16) unsigned short prepC[576];       //  1152 B {w11}
    short* sOMh = sA;   // 27*OMP+12 = 1794 shorts, aliased (sA dead in phase 2)

    const unsigned* xbd = xtb + (size_t)b * HW * 32;               // dword view
    unsigned* sAd = (unsigned*)sA;                                 // row = 100 dw

    // ================= Phase 1: offset conv GEMM (M=64, N=32) ============
    int nt_o = w_s & 1;
    int mh   = w_s >> 1;
    int o_ow = nt_o * 16 + l15;
    f32x4 oacc[2] = {{0,0,0,0},{0,0,0,0}};

    for (int ck = 0; ck < 3; ++ck) {
        int yy = h + ck - 1;
        bool rowok = ((unsigned)yy < (unsigned)Hh);
        // ---- im2col fill: 192 units (kkl(2b)|px(6b)), 8 lanes x dwordx4 each
#pragma unroll
        for (int it = 0; it < 6; ++it) {
            int unit = (it * 4 + w_s) * 8 + og;   // 0..191
            int kkl = unit >> 6, px = unit & 63;
            int xx = px0 + px + kkl - 1;
            bool valid = rowok && ((unsigned)xx < (unsigned)Ww);
            u32x4 v = {0u, 0u, 0u, 0u};
            if (valid)
                v = *(const u32x4*)&xbd[(((size_t)yy << 7) + xx) * 32 + li * 4];
            *(u32x4*)&sAd[px * 100 + kkl * 32 + li * 4] = v;
        }
        __syncthreads();
#pragma unroll
        for (int ks = 0; ks < 6; ++ks) {
            int kk = ck * 3 + (ks >> 1);
            bf16x8 bfr = *(const bf16x8*)&owT[((size_t)o_ow * 9 + kk) * 64
                                             + (ks & 1) * 32 + quad * 8];
#pragma unroll
            for (int m2 = 0; m2 < 2; ++m2) {
                bf16x8 a = *(const bf16x8*)&sA[(mh * 32 + m2 * 16 + l15) * KP
                                               + ks * 32 + quad * 8];
                oacc[m2] = __builtin_amdgcn_mfma_f32_16x16x32_bf16(a, bfr, oacc[m2], 0, 0, 0);
            }
        }
        __syncthreads();
    }
    // ---- D -> sOMh (+bias), f16; px = (mh*2+m2)*16 + quad*4 + r
    if (o_ow < 27) {
        float bias = ob[o_ow];
#pragma unroll
        for (int m2 = 0; m2 < 2; ++m2) {
            int pxb = (mh * 2 + m2) * 16 + quad * 4;
#pragma unroll
            for (int r = 0; r < 4; ++r)
                sOMh[o_ow * OMP + pxb + r] = f2h(oacc[m2][r] + bias);
        }
    }
    __syncthreads();

    // ================= Phase 2: per-thread bilinear prep -> LDS ==========
    // 576 units = tap(9) x px(64); thread owns u = t, t+256, t+512(<576).
    // Validity factorizes per-axis onto physical rows/cols (yb,yb+1)/(xb,xb+1);
    // corner weight = wr*wc, sigmoid mask folded into wr. Base idx yb*128+xb;
    // corners {+0,+1,+128,+129} always in-bounds.
#pragma unroll
    for (int i = 0; i < 3; ++i) {
        int u = t + 256 * i;
        if (u < 576) {
            int kk = u >> 6, px = u & 63;
            float ox = h2f((short)sOMh[kk * OMP + px]);
            float oy = h2f((short)sOMh[(9 + kk) * OMP + px]);
            float mr = h2f((short)sOMh[(18 + kk) * OMP + px]);
            float m  = 1.0f / (1.0f + __expf(-mr));
            float py  = (float)(h - 1 + (kk / 3)) + oy;
            float pxf = (float)(px0 + px - 1 + (kk % 3)) + ox;
            float y0f = floorf(py), x0f = floorf(pxf);
            int y0 = (int)y0f, x0 = (int)x0f;
            float wy = py - y0f, wx = pxf - x0f;
            int yb = min(max(y0, 0), Hh - 2);
            int xb = min(max(x0, 0), Ww - 2);
            float wr0 = (yb == y0) ? (1.0f - wy) : ((yb     == y0 + 1) ? wy : 0.0f);
            float wr1 = (yb == y0) ? wy          : ((yb + 1 == y0    ) ? (1.0f - wy) : 0.0f);
            float wc0 = (xb == x0) ? (1.0f - wx) : ((xb     == x0 + 1) ? wx : 0.0f);
            float wc1 = (xb == x0) ? wx          : ((xb + 1 == x0    ) ? (1.0f - wx) : 0.0f);
            wr0 *= m; wr1 *= m;
            prepQ[u * 4 + 0] = (unsigned short)(yb * Ww + xb);
            prepQ[u * 4 + 1] = (unsigned short)f2h(wr0 * wc0);
            prepQ[u * 4 + 2] = (unsigned short)f2h(wr0 * wc1);
            prepQ[u * 4 + 3] = (unsigned short)f2h(wr1 * wc0);
            prepC[u]         = (unsigned short)f2h(wr1 * wc1);
        }
    }
    __syncthreads();

    // ================= Phase 3: sampling fill + DCN GEMM (M=64, N=64) ====
    // Fill: 8 units per wave-iter (eighth-waves); lane owns 8 CHANNELS
    // (dwordx4). Per unit: b64+b16 broadcast ds_read, ONE gather addr
    // chain, 4x dwordx4 (128B/corner coalesced), 32 FMA, 4x
    // v_cvt_pk_bf16_f32, 1 ds_write_b128. 6 iters (was 12).
    int o_dw = w_s * 16 + l15;
    f32x4 acc[4] = {{0,0,0,0},{0,0,0,0},{0,0,0,0},{0,0,0,0}};

    for (int ck = 0; ck < 3; ++ck) {
#pragma unroll 3
        for (int it = 0; it < 6; ++it) {
            int unit = (it * 4 + w_s) * 8 + ul;   // 0..191 within ck
            int kkl = unit >> 6, px = unit & 63;
            int uG = ck * 192 + unit;             // global unit id
            u16x4 q = *(const u16x4*)&prepQ[uG * 4];     // broadcast ds_read_b64
            float w00 = h2f((short)q[1]);
            float w01 = h2f((short)q[2]);
            float w10 = h2f((short)q[3]);
            float w11 = h2f((short)prepC[uG]);           // broadcast ds_read_u16
            const unsigned* p0 = xbd + (size_t)q[0] * 32 + cl3 * 4;
            u32x4 d00 = *(const u32x4*)(p0);
            u32x4 d01 = *(const u32x4*)(p0 + 32);        // col+1 (+128 B)
            u32x4 d10 = *(const u32x4*)(p0 + 4096);      // row+1
            u32x4 d11 = *(const u32x4*)(p0 + 4128);      // row+1, col+1
            u32x4 pkv;
#pragma unroll
            for (int j = 0; j < 4; ++j) {
                float v0 = w00 * bflo(d00[j]) + w01 * bflo(d01[j])
                         + w10 * bflo(d10[j]) + w11 * bflo(d11[j]);
                float v1 = w00 * bfhi(d00[j]) + w01 * bfhi(d01[j])
                         + w10 * bfhi(d10[j]) + w11 * bfhi(d11[j]);
                unsigned pk;
                asm("v_cvt_pk_bf16_f32 %0, %1, %2" : "=v"(pk) : "v"(v0), "v"(v1));
                pkv[j] = pk;
            }
            *(u32x4*)&sAd[px * 100 + kkl * 32 + cl3 * 4] = pkv;
        }
        __syncthreads();
#pragma unroll
        for (int ks = 0; ks < 6; ++ks) {
            int kk = ck * 3 + (ks >> 1);
            bf16x8 bfr = *(const bf16x8*)&dwT[((size_t)o_dw * 9 + kk) * 64
                                              + (ks & 1) * 32 + quad * 8];
#pragma unroll
            for (int mt = 0; mt < 4; ++mt) {
                bf16x8 a = *(const bf16x8*)&sA[(mt * 16 + l15) * KP
                                               + ks * 32 + quad * 8];
                acc[mt] = __builtin_amdgcn_mfma_f32_16x16x32_bf16(a, bfr, acc[mt], 0, 0, 0);
            }
        }
        __syncthreads();
    }

    // ================= Phase 4: store conv + stats partials =================
#pragma unroll
    for (int mt = 0; mt < 4; ++mt) {
        size_t idx = ((size_t)b * On + o_dw) * HW + (size_t)h * Ww + px0 + mt * 16 + quad * 4;
        *(f32x4*)(conv + idx) = acc[mt];
    }
    float s1 = 0.0f, s2 = 0.0f;
#pragma unroll
    for (int mt = 0; mt < 4; ++mt) {
#pragma unroll
        for (int r = 0; r < 4; ++r) {
            float v = acc[mt][r];
            s1 += v;
            s2 += v * v;
        }
    }
    s1 += __shfl_down(s1, 32, 64);  s2 += __shfl_down(s2, 32, 64);
    s1 += __shfl_down(s1, 16, 64);  s2 += __shfl_down(s2, 16, 64);
    if (lane < 16) {
        part[(size_t)o_dw * NBLK + blk]        = s1;
        part[(size_t)(64 + o_dw) * NBLK + blk] = s2;
    }
}

// ---------------------------------------------------------------------------
// Fused BN stats + apply + ReLU.
// Grid 1024: o = idx&63, bq = idx>>6. Each block re-reduces its channel's
// part rows (8 KB, L2-hit) -> sc/sh, then applies BN+ReLU over a 4096-float
// slab of conv.
// ---------------------------------------------------------------------------
__global__ __launch_bounds__(256) void bnstats_k(
    const float* __restrict__ part, const float* __restrict__ gamma,
    const float* __restrict__ beta, const float* __restrict__ conv,
    float* __restrict__ out)
{
    int idx = blockIdx.x;
    int o  = idx & 63;
    int bq = idx >> 6;          // b = bq>>2, q = bq&3
    int t = threadIdx.x;
    float s1 = 0.0f, s2 = 0.0f;
#pragma unroll
    for (int i = 0; i < NBLK / 256; ++i) {
        int j = t + 256 * i;
        s1 += part[(size_t)o * NBLK + j];
        s2 += part[(size_t)(64 + o) * NBLK + j];
    }
#pragma unroll
    for (int off = 32; off > 0; off >>= 1) {
        s1 += __shfl_down(s1, off, 64);
        s2 += __shfl_down(s2, off, 64);
    }
    __shared__ float r1[4], r2[4];
    __shared__ float sc_s, sh_s;
    if ((t & 63) == 0) { r1[t >> 6] = s1; r2[t >> 6] = s2; }
    __syncthreads();
    if (t == 0) {
        float S1 = r1[0] + r1[1] + r1[2] + r1[3];
        float S2 = r2[0] + r2[1] + r2[2] + r2[3];
        float n = (float)(Bn * HW);
        float mu = S1 / n;
        float var = S2 / n - mu * mu;
        float sc = gamma[o] * rsqrtf(var + 1e-5f);
        sc_s = sc;
        sh_s = beta[o] - mu * sc;
    }
    __syncthreads();
    float sc = sc_s, sh = sh_s;
    size_t base = (((size_t)(bq >> 2) * On + o) * HW + (size_t)(bq & 3) * 4096) / 4;
    const float4* cv = (const float4*)conv + base;
    float4* ov = (float4*)out + base;
#pragma unroll
    for (int i = 0; i < 4; ++i) {
        float4 v = cv[t + 256 * i];
        v.x = fmaxf(v.x * sc + sh, 0.0f);
        v.y = fmaxf(v.y * sc + sh, 0.0f);
        v.z = fmaxf(v.z * sc + sh, 0.0f);
        v.w = fmaxf(v.w * sc + sh, 0.0f);
        ov[t + 256 * i] = v;
    }
}

// ---------------------------------------------------------------------------
extern "C" void kernel_launch(void* const* d_in, const int* in_sizes, int n_in,
                              void* d_out, int out_size, void* d_ws, size_t ws_size,
                              hipStream_t stream)
{
    const float* x     = (const float*)d_in[0];
    const float* ow    = (const float*)d_in[1];
    const float* ob    = (const float*)d_in[2];
    const float* dw    = (const float*)d_in[3];
    // d_in[4] = dcn_b: cancels exactly under BN mean subtraction -> unused
    const float* gamma = (const float*)d_in[5];
    const float* beta  = (const float*)d_in[6];

    char* wsb = (char*)d_ws;
    unsigned* xtb = (unsigned*)wsb;
    float* conv = (float*)(wsb + XTB_BYTES);
    float* part = (float*)(wsb + XTB_BYTES + CONV_BYTES);
    short* owT  = (short*)(wsb + XTB_BYTES + CONV_BYTES + PART_BYTES + 512);
    short* dwT  = owT + 288 * 64;

    prep_k     <<<dim3(728),  dim3(256), 0, stream>>>(x, ow, dw, xtb, owT, dwT);
    dcn_fused_k<<<dim3(NBLK), dim3(256), 0, stream>>>(xtb, owT, ob, dwT, conv, part);
    bnstats_k  <<<dim3(1024), dim3(256), 0, stream>>>(part, gamma, beta, conv, (float*)d_out);
}

// Round 10
// 128.446 us; speedup vs baseline: 1.1745x; 1.0020x over previous
//
#include <hip/hip_runtime.h>
#include <math.h>

#define Hh 128
#define Ww 128
#define HW (Hh*Ww)
#define Bn 4
#define Cn 64
#define On 64
#define KP 200                // LDS A-row stride (shorts): 192 data + 8 pad
                              // (==0 mod 8 for 16B ds_read_b128; row stride
                              //  100 dw == 4 mod 32 banks -> 2-way max = free)
#define OMP 66                // padded px stride for sOM (f16), 64 px
#define NBLK 1024             // dcn grid (half-row blocks)

typedef __attribute__((ext_vector_type(8))) short bf16x8;
typedef __attribute__((ext_vector_type(4))) float f32x4;
typedef __attribute__((ext_vector_type(8))) unsigned short u16x8;
typedef __attribute__((ext_vector_type(4))) unsigned u32x4;

// fp32 -> bf16 round-to-nearest-even
static __device__ __forceinline__ unsigned short f2bf(float f) {
    unsigned u = __builtin_bit_cast(unsigned, f);
    u += 0x7FFFu + ((u >> 16) & 1u);
    return (unsigned short)(u >> 16);
}
static __device__ __forceinline__ short f2h(float f) {
    _Float16 h = (_Float16)f;
    return __builtin_bit_cast(short, h);
}
static __device__ __forceinline__ float h2f(short s) {
    return (float)__builtin_bit_cast(_Float16, s);
}
static __device__ __forceinline__ float h2fu(unsigned short s) {
    return (float)__builtin_bit_cast(_Float16, s);
}
static __device__ __forceinline__ float bflo(unsigned d) {
    return __builtin_bit_cast(float, d << 16);
}
static __device__ __forceinline__ float bfhi(unsigned d) {
    return __builtin_bit_cast(float, d & 0xFFFF0000u);
}

// workspace layout (bytes): xtb(8M) | conv(16M) | part(512K) | ss | owT | dwT
#define XTB_BYTES   ((size_t)Bn*HW*64*2)
#define CONV_BYTES  ((size_t)Bn*On*HW*4)
#define PART_BYTES  ((size_t)128*NBLK*4)

// ---------------------------------------------------------------------------
// Prep: blocks 0..511 = NCHW->NHWC bf16 transpose (one (b,h) row each);
//       blocks 512..727 = weight pack bf16 tap-major [o][tap][c].
// ---------------------------------------------------------------------------
__global__ __launch_bounds__(256) void prep_k(
    const float* __restrict__ x,  const float* __restrict__ ow,
    const float* __restrict__ dw, unsigned* __restrict__ xtb,
    short* __restrict__ owT,      short* __restrict__ dwT)
{
    int blk = blockIdx.x;
    int t = threadIdx.x;
    if (blk < 512) {
        int b = blk >> 7, h = blk & 127;
        __shared__ float sT[64 * 133];
        const float* xp = x + (size_t)b * Cn * HW + (size_t)h * Ww;
#pragma unroll
        for (int it = 0; it < 32; ++it) {
            int idx = t + 256 * it;        // c(6b) | w(7b)
            int c = idx >> 7, w = idx & 127;
            sT[c * 133 + w] = xp[(size_t)c * HW + w];
        }
        __syncthreads();
        unsigned* op = xtb + (size_t)blk * Ww * 32;   // 32 dwords (64 bf16)/px
#pragma unroll
        for (int it = 0; it < 16; ++it) {
            int idx = t + 256 * it;        // w(7b) | cp(5b)
            int w = idx >> 5, cp = idx & 31;
            unsigned lo = f2bf(sT[(2 * cp) * 133 + w]);
            unsigned hi = f2bf(sT[(2 * cp + 1) * 133 + w]);
            op[(size_t)w * 32 + cp] = lo | (hi << 16);
        }
    } else {
        int u = (blk - 512) * 4 + (t >> 6);   // 0..863
        int c = t & 63;
        if (u < 288) {
            int o = u / 9, kk = u % 9;
            float v = (o < 27) ? ow[(size_t)o * 576 + c * 9 + kk] : 0.0f;
            owT[(size_t)u * 64 + c] = (short)f2bf(v);
        } else {
            int u2 = u - 288;
            int o = u2 / 9, kk = u2 % 9;
            dwT[(size_t)u2 * 64 + c] = (short)f2bf(dw[(size_t)o * 576 + c * 9 + kk]);
        }
    }
}

// ---------------------------------------------------------------------------
// Fused: offset-conv GEMM -> per-thread bilinear prep -> sampling fill ->
// DCN GEMM -> conv store + BN stats partials (transposed part).
// Block = HALF-row (64 px), grid 1024, 256 thr / 4 waves. x is bf16 NHWC.
// Structure = R2/R4. LESSONS LEDGER:
//  * R3: barrier-free wave-private flip REGRESSED (per-ks global B-frag
//    loads exposed L2 latency on MFMA path). B streams 1/step; A from LDS.
//  * R5 (8-wave block) & R6 (quarter-row/2048 blocks): BOTH ~67-69 us.
//    Achieved residency pinned ~11-13 waves/CU regardless of theoretical
//    cap; occupancy is NOT the lever. Keep half-row/4-wave/1024.
//  * R7 (cross-barrier prefetch) & R8 (register double-buffer): BOTH
//    defeated -- LLVM sinks pure VMEM loads to their use site (VGPR stayed
//    60 both times). Source-level scheduling does not stick on this kernel.
//  * The ONLY lever that pays: FEWER VMEM/LDS ISSUE EVENTS per unit of
//    work (R1 pair-gather +15us, R4 dwordx2 +6us, R9 dwordx4 +1.3us --
//    width ladder now exhausted at 16B).
// R10 (this round), same lever class, last two un-mined spots:
//  1. Phase-1 im2col: load-once/scatter-3. Iterate 66 SOURCE px, one
//     dwordx4 load each, <=3 conditional b128 ds_writes (px_t = s-kkl).
//     Loads 18 -> 9 iters/wave, staged bytes /3. Coverage: slot (px_t,kkl)
//     <- s=px_t+kkl, written exactly once; OOB sources write zeros exactly
//     as before -> bit-identical.
//  2. prep packed to 8 shorts/unit {idx,w00,w01,w10,w11,0,0,0}: phase-3
//     per-unit broadcast reads b64+b16 -> ONE b128; phase-2 writes one
//     b128/unit. LDS 31.4 -> 34.8 KB (still 4 blocks/CU).
// CRITICAL #1: no __launch_bounds__ min-waves arg (R3 spill disaster).
// CRITICAL #2: wave id readfirstlane'd (R4 divergent-uniform trap).
// MFMA 16x16x32 bf16 (validated R8-R12):
//   A lane=[m=l15][k=quad*8+j]; B lane=[k=quad*8+j][n=l15];
//   D lane=[row=quad*4+r][col=l15].
// LDS: sA 25600 (sOMh 3588 aliased in) + prepP 9216 = 34816 B.
// ---------------------------------------------------------------------------
__global__ __launch_bounds__(256) void dcn_fused_k(
    const unsigned* __restrict__ xtb, const short* __restrict__ owT,
    const float* __restrict__ ob,     const short* __restrict__ dwT,
    float* __restrict__ conv,         float* __restrict__ part)
{
    int raw  = blockIdx.x;
    int blk  = ((raw & 7) << 7) | (raw >> 3);   // b(2b) | h(7b) | half(1b)
    int half = blk & 1;
    int h    = (blk >> 1) & 127;
    int b    = blk >> 8;
    int px0  = half * 64;
    int t    = threadIdx.x;
    int lane = t & 63;
    int quad = lane >> 4;
    int l15  = lane & 15;
    int ul   = lane >> 3;          // eighth-wave unit id (phase 3 fill, 0..7)
    int cl3  = lane & 7;           // dwordx4 (8-channel) group
    int w_s  = __builtin_amdgcn_readfirstlane(t >> 6);   // 0..3 (SGPR)

    __shared__ __align__(16) short sA[64 * KP];               // 25600 B (bf16)
    __shared__ __align__(16) unsigned short prepP[576 * 8];   //  9216 B packed
    short* sOMh = sA;   // 27*OMP+12 = 1794 shorts, aliased (sA dead in phase 2)

    const unsigned* xbd = xtb + (size_t)b * HW * 32;               // dword view
    unsigned* sAd = (unsigned*)sA;                                 // row = 100 dw

    // ================= Phase 1: offset conv GEMM (M=64, N=32) ============
    int nt_o = w_s & 1;
    int mh   = w_s >> 1;
    int o_ow = nt_o * 16 + l15;
    f32x4 oacc[2] = {{0,0,0,0},{0,0,0,0}};

    for (int ck = 0; ck < 3; ++ck) {
        int yy = h + ck - 1;
        bool rowok = ((unsigned)yy < (unsigned)Hh);
        // ---- im2col fill, load-once/scatter-3: 66 source px x 8 ch-groups
        //      = 528 units; u = it*256 + t; slot (px_t=s-kkl, kkl) <- s.
#pragma unroll
        for (int it = 0; it < 3; ++it) {
            int u = it * 256 + t;
            if (u < 528) {
                int s = u >> 3, grp = u & 7;
                int xx = px0 + s - 1;
                bool valid = rowok && ((unsigned)xx < (unsigned)Ww);
                u32x4 v = {0u, 0u, 0u, 0u};
                if (valid)
                    v = *(const u32x4*)&xbd[(((size_t)yy << 7) + xx) * 32 + grp * 4];
#pragma unroll
                for (int kkl = 0; kkl < 3; ++kkl) {
                    int px_t = s - kkl;
                    if (px_t >= 0 && px_t < 64)
                        *(u32x4*)&sAd[px_t * 100 + kkl * 32 + grp * 4] = v;
                }
            }
        }
        __syncthreads();
#pragma unroll
        for (int ks = 0; ks < 6; ++ks) {
            int kk = ck * 3 + (ks >> 1);
            bf16x8 bfr = *(const bf16x8*)&owT[((size_t)o_ow * 9 + kk) * 64
                                             + (ks & 1) * 32 + quad * 8];
#pragma unroll
            for (int m2 = 0; m2 < 2; ++m2) {
                bf16x8 a = *(const bf16x8*)&sA[(mh * 32 + m2 * 16 + l15) * KP
                                               + ks * 32 + quad * 8];
                oacc[m2] = __builtin_amdgcn_mfma_f32_16x16x32_bf16(a, bfr, oacc[m2], 0, 0, 0);
            }
        }
        __syncthreads();
    }
    // ---- D -> sOMh (+bias), f16; px = (mh*2+m2)*16 + quad*4 + r
    if (o_ow < 27) {
        float bias = ob[o_ow];
#pragma unroll
        for (int m2 = 0; m2 < 2; ++m2) {
            int pxb = (mh * 2 + m2) * 16 + quad * 4;
#pragma unroll
            for (int r = 0; r < 4; ++r)
                sOMh[o_ow * OMP + pxb + r] = f2h(oacc[m2][r] + bias);
        }
    }
    __syncthreads();

    // ================= Phase 2: per-thread bilinear prep -> LDS ==========
    // 576 units = tap(9) x px(64); thread owns u = t, t+256, t+512(<576).
    // Validity factorizes per-axis onto physical rows/cols (yb,yb+1)/(xb,xb+1);
    // corner weight = wr*wc, sigmoid mask folded into wr. Base idx yb*128+xb;
    // corners {+0,+1,+128,+129} always in-bounds. One b128 write per unit.
#pragma unroll
    for (int i = 0; i < 3; ++i) {
        int u = t + 256 * i;
        if (u < 576) {
            int kk = u >> 6, px = u & 63;
            float ox = h2f((short)sOMh[kk * OMP + px]);
            float oy = h2f((short)sOMh[(9 + kk) * OMP + px]);
            float mr = h2f((short)sOMh[(18 + kk) * OMP + px]);
            float m  = 1.0f / (1.0f + __expf(-mr));
            float py  = (float)(h - 1 + (kk / 3)) + oy;
            float pxf = (float)(px0 + px - 1 + (kk % 3)) + ox;
            float y0f = floorf(py), x0f = floorf(pxf);
            int y0 = (int)y0f, x0 = (int)x0f;
            float wy = py - y0f, wx = pxf - x0f;
            int yb = min(max(y0, 0), Hh - 2);
            int xb = min(max(x0, 0), Ww - 2);
            float wr0 = (yb == y0) ? (1.0f - wy) : ((yb     == y0 + 1) ? wy : 0.0f);
            float wr1 = (yb == y0) ? wy          : ((yb + 1 == y0    ) ? (1.0f - wy) : 0.0f);
            float wc0 = (xb == x0) ? (1.0f - wx) : ((xb     == x0 + 1) ? wx : 0.0f);
            float wc1 = (xb == x0) ? wx          : ((xb + 1 == x0    ) ? (1.0f - wx) : 0.0f);
            wr0 *= m; wr1 *= m;
            u16x8 pk8;
            pk8[0] = (unsigned short)(yb * Ww + xb);
            pk8[1] = (unsigned short)f2h(wr0 * wc0);
            pk8[2] = (unsigned short)f2h(wr0 * wc1);
            pk8[3] = (unsigned short)f2h(wr1 * wc0);
            pk8[4] = (unsigned short)f2h(wr1 * wc1);
            pk8[5] = 0; pk8[6] = 0; pk8[7] = 0;
            *(u16x8*)&prepP[u * 8] = pk8;
        }
    }
    __syncthreads();

    // ================= Phase 3: sampling fill + DCN GEMM (M=64, N=64) ====
    // Fill: 8 units per wave-iter (eighth-waves); lane owns 8 CHANNELS
    // (dwordx4). Per unit: ONE b128 broadcast ds_read (packed prep), ONE
    // gather addr chain, 4x dwordx4 (128B/corner coalesced), 32 FMA, 4x
    // v_cvt_pk_bf16_f32, 1 ds_write_b128. 6 iters.
    int o_dw = w_s * 16 + l15;
    f32x4 acc[4] = {{0,0,0,0},{0,0,0,0},{0,0,0,0},{0,0,0,0}};

    for (int ck = 0; ck < 3; ++ck) {
#pragma unroll 3
        for (int it = 0; it < 6; ++it) {
            int unit = (it * 4 + w_s) * 8 + ul;   // 0..191 within ck
            int kkl = unit >> 6, px = unit & 63;
            int uG = ck * 192 + unit;             // global unit id
            u16x8 q = *(const u16x8*)&prepP[uG * 8];     // ONE broadcast b128
            float w00 = h2fu(q[1]);
            float w01 = h2fu(q[2]);
            float w10 = h2fu(q[3]);
            float w11 = h2fu(q[4]);
            const unsigned* p0 = xbd + (size_t)q[0] * 32 + cl3 * 4;
            u32x4 d00 = *(const u32x4*)(p0);
            u32x4 d01 = *(const u32x4*)(p0 + 32);        // col+1 (+128 B)
            u32x4 d10 = *(const u32x4*)(p0 + 4096);      // row+1
            u32x4 d11 = *(const u32x4*)(p0 + 4128);      // row+1, col+1
            u32x4 pkv;
#pragma unroll
            for (int j = 0; j < 4; ++j) {
                float v0 = w00 * bflo(d00[j]) + w01 * bflo(d01[j])
                         + w10 * bflo(d10[j]) + w11 * bflo(d11[j]);
                float v1 = w00 * bfhi(d00[j]) + w01 * bfhi(d01[j])
                         + w10 * bfhi(d10[j]) + w11 * bfhi(d11[j]);
                unsigned pk;
                asm("v_cvt_pk_bf16_f32 %0, %1, %2" : "=v"(pk) : "v"(v0), "v"(v1));
                pkv[j] = pk;
            }
            *(u32x4*)&sAd[px * 100 + kkl * 32 + cl3 * 4] = pkv;
        }
        __syncthreads();
#pragma unroll
        for (int ks = 0; ks < 6; ++ks) {
            int kk = ck * 3 + (ks >> 1);
            bf16x8 bfr = *(const bf16x8*)&dwT[((size_t)o_dw * 9 + kk) * 64
                                              + (ks & 1) * 32 + quad * 8];
#pragma unroll
            for (int mt = 0; mt < 4; ++mt) {
                bf16x8 a = *(const bf16x8*)&sA[(mt * 16 + l15) * KP
                                               + ks * 32 + quad * 8];
                acc[mt] = __builtin_amdgcn_mfma_f32_16x16x32_bf16(a, bfr, acc[mt], 0, 0, 0);
            }
        }
        __syncthreads();
    }

    // ================= Phase 4: store conv + stats partials =================
#pragma unroll
    for (int mt = 0; mt < 4; ++mt) {
        size_t idx = ((size_t)b * On + o_dw) * HW + (size_t)h * Ww + px0 + mt * 16 + quad * 4;
        *(f32x4*)(conv + idx) = acc[mt];
    }
    float s1 = 0.0f, s2 = 0.0f;
#pragma unroll
    for (int mt = 0; mt < 4; ++mt) {
#pragma unroll
        for (int r = 0; r < 4; ++r) {
            float v = acc[mt][r];
            s1 += v;
            s2 += v * v;
        }
    }
    s1 += __shfl_down(s1, 32, 64);  s2 += __shfl_down(s2, 32, 64);
    s1 += __shfl_down(s1, 16, 64);  s2 += __shfl_down(s2, 16, 64);
    if (lane < 16) {
        part[(size_t)o_dw * NBLK + blk]        = s1;
        part[(size_t)(64 + o_dw) * NBLK + blk] = s2;
    }
}

// ---------------------------------------------------------------------------
// Fused BN stats + apply + ReLU.
// Grid 1024: o = idx&63, bq = idx>>6. Each block re-reduces its channel's
// part rows (8 KB, L2-hit) -> sc/sh, then applies BN+ReLU over a 4096-float
// slab of conv.
// ---------------------------------------------------------------------------
__global__ __launch_bounds__(256) void bnstats_k(
    const float* __restrict__ part, const float* __restrict__ gamma,
    const float* __restrict__ beta, const float* __restrict__ conv,
    float* __restrict__ out)
{
    int idx = blockIdx.x;
    int o  = idx & 63;
    int bq = idx >> 6;          // b = bq>>2, q = bq&3
    int t = threadIdx.x;
    float s1 = 0.0f, s2 = 0.0f;
#pragma unroll
    for (int i = 0; i < NBLK / 256; ++i) {
        int j = t + 256 * i;
        s1 += part[(size_t)o * NBLK + j];
        s2 += part[(size_t)(64 + o) * NBLK + j];
    }
#pragma unroll
    for (int off = 32; off > 0; off >>= 1) {
        s1 += __shfl_down(s1, off, 64);
        s2 += __shfl_down(s2, off, 64);
    }
    __shared__ float r1[4], r2[4];
    __shared__ float sc_s, sh_s;
    if ((t & 63) == 0) { r1[t >> 6] = s1; r2[t >> 6] = s2; }
    __syncthreads();
    if (t == 0) {
        float S1 = r1[0] + r1[1] + r1[2] + r1[3];
        float S2 = r2[0] + r2[1] + r2[2] + r2[3];
        float n = (float)(Bn * HW);
        float mu = S1 / n;
        float var = S2 / n - mu * mu;
        float sc = gamma[o] * rsqrtf(var + 1e-5f);
        sc_s = sc;
        sh_s = beta[o] - mu * sc;
    }
    __syncthreads();
    float sc = sc_s, sh = sh_s;
    size_t base = (((size_t)(bq >> 2) * On + o) * HW + (size_t)(bq & 3) * 4096) / 4;
    const float4* cv = (const float4*)conv + base;
    float4* ov = (float4*)out + base;
#pragma unroll
    for (int i = 0; i < 4; ++i) {
        float4 v = cv[t + 256 * i];
        v.x = fmaxf(v.x * sc + sh, 0.0f);
        v.y = fmaxf(v.y * sc + sh, 0.0f);
        v.z = fmaxf(v.z * sc + sh, 0.0f);
        v.w = fmaxf(v.w * sc + sh, 0.0f);
        ov[t + 256 * i] = v;
    }
}

// ---------------------------------------------------------------------------
extern "C" void kernel_launch(void* const* d_in, const int* in_sizes, int n_in,
                              void* d_out, int out_size, void* d_ws, size_t ws_size,
                              hipStream_t stream)
{
    const float* x     = (const float*)d_in[0];
    const float* ow    = (const float*)d_in[1];
    const float* ob    = (const float*)d_in[2];
    const float* dw    = (const float*)d_in[3];
    // d_in[4] = dcn_b: cancels exactly under BN mean subtraction -> unused
    const float* gamma = (const float*)d_in[5];
    const float* beta  = (const float*)d_in[6];

    char* wsb = (char*)d_ws;
    unsigned* xtb = (unsigned*)wsb;
    float* conv = (float*)(wsb + XTB_BYTES);
    float* part = (float*)(wsb + XTB_BYTES + CONV_BYTES);
    short* owT  = (short*)(wsb + XTB_BYTES + CONV_BYTES + PART_BYTES + 512);
    short* dwT  = owT + 288 * 64;

    prep_k     <<<dim3(728),  dim3(256), 0, stream>>>(x, ow, dw, xtb, owT, dwT);
    dcn_fused_k<<<dim3(NBLK), dim3(256), 0, stream>>>(xtb, owT, ob, dwT, conv, part);
    bnstats_k  <<<dim3(1024), dim3(256), 0, stream>>>(part, gamma, beta, conv, (float*)d_out);
}